// Round 3
// baseline (5044.571 us; speedup 1.0000x reference)
//
#include <hip/hip_runtime.h>
#include <hip/hip_bf16.h>
#include <math.h>

typedef __hip_bfloat16 bf16;

__device__ __forceinline__ float b2f(bf16 x) { return __bfloat162float(x); }
__device__ __forceinline__ bf16 f2b(float x) { return __float2bfloat16(x); }

// Problem constants
constexpr int Bn = 4, Tn = 2048, Dn = 1024, KDn = 512, VDn = 1024;
constexpr int Hn = 4, Mn = 64, HKn = 128, HVn = 256;
constexpr int BT = Bn * Tn; // 8192

// ---------------------------------------------------------------------------
// Dtype probe: read x as bf16. If the buffer actually holds fp32, the low
// halves of each float are mantissa garbage with random exponents -> max huge.
// flag = 1 (fp32 inputs) if max > 1e6, else 0 (bf16 inputs).
// ---------------------------------------------------------------------------
__global__ __launch_bounds__(256) void probe_dtype_kernel(
    const void* __restrict__ x, int* __restrict__ flag)
{
    const bf16* xb = (const bf16*)x;
    float mx = 0.f;
    for (int i = threadIdx.x; i < 4096; i += 256) {
        float v = fabsf(b2f(xb[i]));
        if (isnan(v)) v = 1e30f;
        mx = fmaxf(mx, v);
    }
    __shared__ float red[256];
    red[threadIdx.x] = mx;
    __syncthreads();
    for (int s = 128; s > 0; s >>= 1) {
        if (threadIdx.x < s) red[threadIdx.x] = fmaxf(red[threadIdx.x], red[threadIdx.x + s]);
        __syncthreads();
    }
    if (threadIdx.x == 0) flag[0] = (red[0] > 1e6f) ? 1 : 0;
}

// Convert any input to canonical bf16 per flag.
__global__ __launch_bounds__(256) void convert_kernel(
    const void* __restrict__ src, bf16* __restrict__ dst,
    const int* __restrict__ flag, int n)
{
    int is32 = flag[0];
    int i0 = (blockIdx.x * 256 + threadIdx.x) * 4;
#pragma unroll
    for (int j = 0; j < 4; j++) {
        int i = i0 + j;
        if (i < n)
            dst[i] = is32 ? f2b(((const float*)src)[i]) : ((const bf16*)src)[i];
    }
}

// ---------------------------------------------------------------------------
// Tiled GEMM: C[M,N] = A[M,K](bf16) * B[K,N](bf16), fp32 accumulate.
// 128x128 tile, 256 threads, 8x8 per thread.
// EP: 0 = store bf16, 1 = store fp32, 2 = store bf16(exp(clip(x,-32,32))),
//     3 = dynamic (flag: 1 -> fp32, 0 -> bf16)
// ---------------------------------------------------------------------------
template <int EP>
__global__ __launch_bounds__(256) void gemm_kernel(
    const bf16* __restrict__ A, const bf16* __restrict__ B,
    void* __restrict__ Cout, const int* __restrict__ flag,
    int M, int N, int K)
{
    __shared__ float As[16][129];
    __shared__ float Bs[16][129];
    const int tid = threadIdx.x;
    const int tx = tid & 15, ty = tid >> 4;
    const int m0 = blockIdx.y * 128, n0 = blockIdx.x * 128;
    const int ak = tid & 15;
    const int ar = tid >> 4;
    const int bn = tid & 127;
    const int bk0 = tid >> 7;
    int dyn = 0;
    if (EP == 3) dyn = flag[0];

    float acc[8][8] = {};
    for (int k0 = 0; k0 < K; k0 += 16) {
#pragma unroll
        for (int i = 0; i < 8; i++)
            As[ak][ar + 16 * i] = b2f(A[(size_t)(m0 + ar + 16 * i) * K + k0 + ak]);
#pragma unroll
        for (int i = 0; i < 8; i++)
            Bs[bk0 + 2 * i][bn] = b2f(B[(size_t)(k0 + bk0 + 2 * i) * N + n0 + bn]);
        __syncthreads();
#pragma unroll
        for (int kk = 0; kk < 16; kk++) {
            float a[8], bb[8];
#pragma unroll
            for (int i = 0; i < 8; i++) a[i] = As[kk][ty + 16 * i];
#pragma unroll
            for (int j = 0; j < 8; j++) bb[j] = Bs[kk][tx + 16 * j];
#pragma unroll
            for (int i = 0; i < 8; i++)
#pragma unroll
                for (int j = 0; j < 8; j++)
                    acc[i][j] += a[i] * bb[j];
        }
        __syncthreads();
    }
#pragma unroll
    for (int i = 0; i < 8; i++)
#pragma unroll
        for (int j = 0; j < 8; j++) {
            size_t idx = (size_t)(m0 + ty + 16 * i) * N + n0 + tx + 16 * j;
            float v = acc[i][j];
            if (EP == 1) {
                ((float*)Cout)[idx] = v;
            } else if (EP == 2) {
                float cl = fminf(32.f, fmaxf(-32.f, v));
                ((bf16*)Cout)[idx] = f2b(expf(cl));
            } else if (EP == 3) {
                if (dyn) ((float*)Cout)[idx] = v;
                else ((bf16*)Cout)[idx] = f2b(v);
            } else {
                ((bf16*)Cout)[idx] = f2b(v);
            }
        }
}

// ---------------------------------------------------------------------------
// Depthwise causal conv (KS=4) + SiLU + RoPE, for q/k (C=512, hk=128).
// pre is fp32. One thread handles a rotation pair (d, d+64) within a head.
// ---------------------------------------------------------------------------
__global__ __launch_bounds__(256) void conv_qk_rope_kernel(
    const float* __restrict__ pre, const bf16* __restrict__ w,
    bf16* __restrict__ out)
{
    int gid = blockIdx.x * 256 + threadIdx.x;  // B*T*H*64 = 2,097,152
    int d = gid & 63;
    int h = (gid >> 6) & 3;
    int t = (gid >> 8) & 2047;
    int b = gid >> 19;
    int clo = h * HKn + d, chi = clo + 64;
    float ylo = 0.f, yhi = 0.f;
#pragma unroll
    for (int j = 0; j < 4; j++) {
        int tt = t - 3 + j;
        if (tt >= 0) {
            size_t rb = (size_t)(b * Tn + tt) * KDn;
            ylo += pre[rb + clo] * b2f(w[clo * 4 + j]);
            yhi += pre[rb + chi] * b2f(w[chi * 4 + j]);
        }
    }
    ylo = ylo / (1.f + expf(-ylo));   // silu
    yhi = yhi / (1.f + expf(-yhi));
    float invf = powf(10000.f, -(float)d * (1.f / 64.f));
    float th = (float)t * invf;
    float c = cosf(th), s = sinf(th);
    size_t rowbase = (size_t)(b * Tn + t) * KDn;
    out[rowbase + clo] = f2b(ylo * c - yhi * s);
    out[rowbase + chi] = f2b(yhi * c + ylo * s);
}

// conv + silu for v (C=1024), no rope; pre is bf16
__global__ __launch_bounds__(256) void conv_v_kernel(
    const bf16* __restrict__ pre, const bf16* __restrict__ w,
    bf16* __restrict__ out)
{
    int gid = blockIdx.x * 256 + threadIdx.x;  // B*T*1024 = 8,388,608
    int c = gid & 1023;
    int t = (gid >> 10) & 2047;
    int b = gid >> 21;
    float y = 0.f;
#pragma unroll
    for (int j = 0; j < 4; j++) {
        int tt = t - 3 + j;
        if (tt >= 0)
            y += b2f(pre[(size_t)(b * Tn + tt) * VDn + c]) * b2f(w[c * 4 + j]);
    }
    y = y / (1.f + expf(-y));
    out[(size_t)(b * Tn + t) * VDn + c] = f2b(y);
}

// ---------------------------------------------------------------------------
// C = cumsum_t(E) per (b,h,m), accumulating the bf16-ROUNDED E so E/C
// ratios stay self-consistent downstream.  (E was written by gemm<EP=2>.)
// ---------------------------------------------------------------------------
__global__ __launch_bounds__(256) void cumsum_kernel(
    const bf16* __restrict__ E, float* __restrict__ C)
{
    int gid = blockIdx.x * 256 + threadIdx.x;  // 1024 columns
    int b = gid >> 8;
    int hm = gid & 255;
    size_t base = (size_t)b * Tn * (Hn * Mn) + hm;
    float run = 0.f;
    for (int t = 0; t < Tn; t++) {
        run += b2f(E[base + (size_t)t * 256]);
        C[base + (size_t)t * 256] = run;
    }
}

// ---------------------------------------------------------------------------
// attn1: ok[t,m] = scale * (sum_{tau<=t} (q_t.k_tau) E[tau,m]) / C[t,m]
//        u[t,m]  = softmax_m(ok)[t,m] / C[t,m]
// grid (T/64, B*H), block 256. 64-row tile per block.
// ---------------------------------------------------------------------------
__global__ __launch_bounds__(256) void attn1_kernel(
    const bf16* __restrict__ Q, const bf16* __restrict__ K,
    const bf16* __restrict__ E, const float* __restrict__ C,
    float* __restrict__ U)
{
    __shared__ float Qc[64][33];
    __shared__ float Kc[64][33];
    __shared__ float Ss[64][65];
    __shared__ float Es[64][65];
    const int tid = threadIdx.x;
    const int tx = tid & 15, ty = tid >> 4;
    const int t0 = blockIdx.x * 64;
    const int b = blockIdx.y >> 2, h = blockIdx.y & 3;

    float okacc[4][4] = {};
    for (int tau0 = 0; tau0 <= t0; tau0 += 64) {
        float Sacc[4][4] = {};
        for (int kc = 0; kc < HKn; kc += 32) {
#pragma unroll
            for (int i = 0; i < 8; i++) {
                int e = tid + 256 * i;
                int r = e >> 5, c = e & 31;
                Qc[r][c] = b2f(Q[(size_t)(b * Tn + t0 + r) * KDn + h * HKn + kc + c]);
                Kc[r][c] = b2f(K[(size_t)(b * Tn + tau0 + r) * KDn + h * HKn + kc + c]);
            }
            __syncthreads();
#pragma unroll
            for (int kk = 0; kk < 32; kk++) {
                float a[4], bb[4];
#pragma unroll
                for (int i = 0; i < 4; i++) a[i] = Qc[ty + 16 * i][kk];
#pragma unroll
                for (int j = 0; j < 4; j++) bb[j] = Kc[tx + 16 * j][kk];
#pragma unroll
                for (int i = 0; i < 4; i++)
#pragma unroll
                    for (int j = 0; j < 4; j++) Sacc[i][j] += a[i] * bb[j];
            }
            __syncthreads();
        }
#pragma unroll
        for (int i = 0; i < 4; i++)
#pragma unroll
            for (int j = 0; j < 4; j++) {
                bool valid = (tau0 + tx + 16 * j) <= (t0 + ty + 16 * i);
                Ss[ty + 16 * i][tx + 16 * j] = valid ? Sacc[i][j] : 0.f;
            }
#pragma unroll
        for (int i = 0; i < 16; i++) {
            int e = tid + 256 * i;
            int r = e >> 6, m = e & 63;
            Es[r][m] = b2f(E[(size_t)(b * Tn + tau0 + r) * 256 + h * Mn + m]);
        }
        __syncthreads();
#pragma unroll
        for (int kk = 0; kk < 64; kk++) {
            float a[4], bb[4];
#pragma unroll
            for (int i = 0; i < 4; i++) a[i] = Ss[ty + 16 * i][kk];
#pragma unroll
            for (int j = 0; j < 4; j++) bb[j] = Es[kk][tx + 16 * j];
#pragma unroll
            for (int i = 0; i < 4; i++)
#pragma unroll
                for (int j = 0; j < 4; j++) okacc[i][j] += a[i] * bb[j];
        }
        __syncthreads();
    }
#pragma unroll
    for (int i = 0; i < 4; i++)
#pragma unroll
        for (int j = 0; j < 4; j++)
            Ss[ty + 16 * i][tx + 16 * j] = okacc[i][j];
    __syncthreads();
    if (tid < 64) {
        int t = t0 + tid;
        size_t base = (size_t)(b * Tn + t) * 256 + h * Mn;
        const float scale = 0.08838834764831845f;  // 1/sqrt(128)
        float mx = -1e30f;
        for (int m = 0; m < 64; m++) {
            float v = Ss[tid][m] * scale / C[base + m];
            Ss[tid][m] = v;
            mx = fmaxf(mx, v);
        }
        float sum = 0.f;
        for (int m = 0; m < 64; m++) {
            float e = expf(Ss[tid][m] - mx);
            Ss[tid][m] = e;
            sum += e;
        }
        float inv = 1.f / sum;
        for (int m = 0; m < 64; m++)
            U[base + m] = Ss[tid][m] * inv / C[base + m];
    }
}

// ---------------------------------------------------------------------------
// attn2: P[t,tau] = sum_m u[t,m] E[tau,m] (causal);  ov[t,:] += P @ V
// ---------------------------------------------------------------------------
__global__ __launch_bounds__(256) void attn2_kernel(
    const float* __restrict__ U, const bf16* __restrict__ E,
    const bf16* __restrict__ V, bf16* __restrict__ OV)
{
    __shared__ float Us[64][65];
    __shared__ bf16 Esb[64][66];
    __shared__ float Ps[64][65];
    __shared__ float Vs[64][65];
    const int tid = threadIdx.x;
    const int tx = tid & 15, ty = tid >> 4;
    const int t0 = blockIdx.x * 64;
    const int b = blockIdx.y >> 2, h = blockIdx.y & 3;

    float ovacc[4][16] = {};
#pragma unroll
    for (int i = 0; i < 16; i++) {
        int e = tid + 256 * i;
        int r = e >> 6, m = e & 63;
        Us[r][m] = U[(size_t)(b * Tn + t0 + r) * 256 + h * Mn + m];
    }
    for (int tau0 = 0; tau0 <= t0; tau0 += 64) {
#pragma unroll
        for (int i = 0; i < 16; i++) {
            int e = tid + 256 * i;
            int r = e >> 6, m = e & 63;
            Esb[r][m] = E[(size_t)(b * Tn + tau0 + r) * 256 + h * Mn + m];
        }
        __syncthreads();
        float Pacc[4][4] = {};
#pragma unroll
        for (int m = 0; m < 64; m++) {
            float a[4], bb[4];
#pragma unroll
            for (int i = 0; i < 4; i++) a[i] = Us[ty + 16 * i][m];
#pragma unroll
            for (int j = 0; j < 4; j++) bb[j] = b2f(Esb[tx + 16 * j][m]);
#pragma unroll
            for (int i = 0; i < 4; i++)
#pragma unroll
                for (int j = 0; j < 4; j++) Pacc[i][j] += a[i] * bb[j];
        }
#pragma unroll
        for (int i = 0; i < 4; i++)
#pragma unroll
            for (int j = 0; j < 4; j++) {
                bool valid = (tau0 + tx + 16 * j) <= (t0 + ty + 16 * i);
                Ps[ty + 16 * i][tx + 16 * j] = valid ? Pacc[i][j] : 0.f;
            }
        for (int vc = 0; vc < 4; vc++) {
#pragma unroll
            for (int i = 0; i < 16; i++) {
                int e = tid + 256 * i;
                int r = e >> 6, c = e & 63;
                Vs[r][c] = b2f(V[(size_t)(b * Tn + tau0 + r) * VDn + h * HVn + vc * 64 + c]);
            }
            __syncthreads();
#pragma unroll
            for (int kk = 0; kk < 64; kk++) {
                float p[4], vv[4];
#pragma unroll
                for (int i = 0; i < 4; i++) p[i] = Ps[ty + 16 * i][kk];
#pragma unroll
                for (int j = 0; j < 4; j++) vv[j] = Vs[kk][tx + 16 * j];
#pragma unroll
                for (int i = 0; i < 4; i++)
#pragma unroll
                    for (int j = 0; j < 4; j++) ovacc[i][vc * 4 + j] += p[i] * vv[j];
            }
            __syncthreads();
        }
    }
#pragma unroll
    for (int i = 0; i < 4; i++)
#pragma unroll
        for (int jj = 0; jj < 16; jj++) {
            int vcol = (jj >> 2) * 64 + (jj & 3) * 16 + tx;
            OV[(size_t)(b * Tn + t0 + ty + 16 * i) * VDn + h * HVn + vcol] = f2b(ovacc[i][jj]);
        }
}

// ---------------------------------------------------------------------------
// Per-(b,t,h) RMS norm over hv=256, * gnorm_w * silu(g). IN-PLACE on OV.
// ---------------------------------------------------------------------------
__global__ __launch_bounds__(256) void norm_gate_kernel(
    bf16* __restrict__ OV, const bf16* __restrict__ G,
    const bf16* __restrict__ gn)
{
    int gid = blockIdx.x;            // B*T*H = 32768
    int h = gid & 3;
    int t = (gid >> 2) & 2047;
    int b = gid >> 13;
    int v = threadIdx.x;
    size_t idx = (size_t)(b * Tn + t) * VDn + h * HVn + v;
    float val = b2f(OV[idx]);
    float ss = val * val;
#pragma unroll
    for (int off = 32; off > 0; off >>= 1) ss += __shfl_down(ss, off, 64);
    __shared__ float red[4];
    int lane = threadIdx.x & 63, wid = threadIdx.x >> 6;
    if (lane == 0) red[wid] = ss;
    __syncthreads();
    float tot = red[0] + red[1] + red[2] + red[3];
    float rs = rsqrtf(tot * (1.0f / 256.0f) + 1e-5f);
    float g = b2f(G[idx]);
    float sg = g / (1.f + expf(-g));
    OV[idx] = f2b(val * rs * b2f(gn[v]) * sg);
}

// ---------------------------------------------------------------------------
extern "C" void kernel_launch(void* const* d_in, const int* in_sizes, int n_in,
                              void* d_out, int out_size, void* d_ws, size_t ws_size,
                              hipStream_t stream)
{
    constexpr size_t MB = 1u << 20;
    char* w = (char*)d_ws;
    // canonical bf16 inputs
    bf16* Xb   = (bf16*)(w + 0);              // [0,16)MB
    bf16* Wob  = (bf16*)(w + 16 * MB);        // [16,18)
    bf16* gnwb = (bf16*)(w + 18 * MB);        // 512 B
    bf16* qwb  = (bf16*)(w + 18 * MB + 4096);
    bf16* kwb  = (bf16*)(w + 18 * MB + 8192);
    bf16* vwb  = (bf16*)(w + 18 * MB + 16384);
    bf16* Wqb  = (bf16*)(w + 19 * MB);
    bf16* Wkb  = (bf16*)(w + 20 * MB);
    bf16* Wvb  = (bf16*)(w + 21 * MB);        // 2MB
    bf16* Wsb  = (bf16*)(w + 23 * MB);        // 0.5MB
    bf16* Wgb  = (bf16*)(w + 24 * MB);        // 2MB
    // activations (stream-ordered reuse)
    float* preF = (float*)(w + 26 * MB);      // [26,42) q/k pre fp32
    bf16*  preB = (bf16*) (w + 26 * MB);      // [26,42) v pre bf16
    float* Cbuf = (float*)(w + 26 * MB);      // [26,34) after convs
    float* Ubuf = (float*)(w + 34 * MB);      // [34,42)
    bf16*  ghat = (bf16*) (w + 26 * MB);      // [26,42) after attn2
    bf16*  Qb   = (bf16*) (w + 42 * MB);      // [42,50)
    bf16*  Kb   = (bf16*) (w + 50 * MB);      // [50,58)
    bf16*  OVb  = (bf16*) (w + 42 * MB);      // [42,58) after attn1
    bf16*  Ebuf = (bf16*) (w + 58 * MB);      // [58,62)
    int*   flagp = (int*) (w + 62 * MB);
    bf16*  Vb   = (bf16*)d_out;               // stage V in d_out (dead before final write)

    dim3 blk(256);
    // dtype probe + canonicalization
    probe_dtype_kernel<<<1, blk, 0, stream>>>(d_in[0], flagp);
    convert_kernel<<<8192, blk, 0, stream>>>(d_in[0], Xb,   flagp, BT * Dn);
    convert_kernel<<<512,  blk, 0, stream>>>(d_in[1], Wqb,  flagp, Dn * KDn);
    convert_kernel<<<512,  blk, 0, stream>>>(d_in[2], Wkb,  flagp, Dn * KDn);
    convert_kernel<<<1024, blk, 0, stream>>>(d_in[3], Wvb,  flagp, Dn * VDn);
    convert_kernel<<<256,  blk, 0, stream>>>(d_in[4], Wsb,  flagp, Dn * 256);
    convert_kernel<<<1024, blk, 0, stream>>>(d_in[5], Wgb,  flagp, Dn * VDn);
    convert_kernel<<<1024, blk, 0, stream>>>(d_in[6], Wob,  flagp, VDn * Dn);
    convert_kernel<<<2,    blk, 0, stream>>>(d_in[7], qwb,  flagp, KDn * 4);
    convert_kernel<<<2,    blk, 0, stream>>>(d_in[8], kwb,  flagp, KDn * 4);
    convert_kernel<<<4,    blk, 0, stream>>>(d_in[9], vwb,  flagp, VDn * 4);
    convert_kernel<<<1,    blk, 0, stream>>>(d_in[10], gnwb, flagp, HVn);
    // q path
    gemm_kernel<1><<<dim3(4, 64), blk, 0, stream>>>(Xb, Wqb, preF, nullptr, BT, KDn, Dn);
    conv_qk_rope_kernel<<<8192, blk, 0, stream>>>(preF, qwb, Qb);
    // k path
    gemm_kernel<1><<<dim3(4, 64), blk, 0, stream>>>(Xb, Wkb, preF, nullptr, BT, KDn, Dn);
    conv_qk_rope_kernel<<<8192, blk, 0, stream>>>(preF, kwb, Kb);
    // v path (pre in bf16, staged V in d_out)
    gemm_kernel<0><<<dim3(8, 64), blk, 0, stream>>>(Xb, Wvb, preB, nullptr, BT, VDn, Dn);
    conv_v_kernel<<<32768, blk, 0, stream>>>(preB, vwb, Vb);
    // slot gates: E = exp(clip(X@Ws)) fused in GEMM epilogue; then cumsum -> C
    gemm_kernel<2><<<dim3(2, 64), blk, 0, stream>>>(Xb, Wsb, Ebuf, nullptr, BT, 256, Dn);
    cumsum_kernel<<<4, blk, 0, stream>>>(Ebuf, Cbuf);
    // two attention-form passes
    attn1_kernel<<<dim3(Tn / 64, Bn * Hn), blk, 0, stream>>>(Qb, Kb, Ebuf, Cbuf, Ubuf);
    attn2_kernel<<<dim3(Tn / 64, Bn * Hn), blk, 0, stream>>>(Ubuf, Ebuf, Vb, OVb);
    // gate projection (over dead C/U region)
    gemm_kernel<0><<<dim3(8, 64), blk, 0, stream>>>(Xb, Wgb, ghat, nullptr, BT, VDn, Dn);
    // norm * gate, in place on OVb
    norm_gate_kernel<<<32768, blk, 0, stream>>>(OVb, ghat, gnwb);
    // output projection; store dtype per flag
    gemm_kernel<3><<<dim3(8, 64), blk, 0, stream>>>(OVb, Wob, d_out, flagp, BT, Dn, VDn);
}

// Round 4
// 880.787 us; speedup vs baseline: 5.7273x; 5.7273x over previous
//
#include <hip/hip_runtime.h>
#include <hip/hip_bf16.h>
#include <math.h>

typedef __hip_bfloat16 bf16;
typedef short s8v __attribute__((ext_vector_type(8)));
typedef float f4v __attribute__((ext_vector_type(4)));

__device__ __forceinline__ float b2f(bf16 x) { return __bfloat162float(x); }
__device__ __forceinline__ bf16 f2b(float x) { return __float2bfloat16(x); }
__device__ __forceinline__ f4v mfma16(s8v a, s8v b, f4v c) {
    return __builtin_amdgcn_mfma_f32_16x16x32_bf16(a, b, c, 0, 0, 0);
}

// Problem constants
constexpr int Bn = 4, Tn = 2048, Dn = 1024, KDn = 512, VDn = 1024;
constexpr int Hn = 4, Mn = 64, HKn = 128, HVn = 256;
constexpr int BT = Bn * Tn; // 8192

// ---------------------------------------------------------------------------
// Dtype probe (fp32 vs bf16 inputs) — see round-3 rationale.
// ---------------------------------------------------------------------------
__global__ __launch_bounds__(256) void probe_dtype_kernel(
    const void* __restrict__ x, int* __restrict__ flag)
{
    const bf16* xb = (const bf16*)x;
    float mx = 0.f;
    for (int i = threadIdx.x; i < 4096; i += 256) {
        float v = fabsf(b2f(xb[i]));
        if (isnan(v)) v = 1e30f;
        mx = fmaxf(mx, v);
    }
    __shared__ float red[256];
    red[threadIdx.x] = mx;
    __syncthreads();
    for (int s = 128; s > 0; s >>= 1) {
        if (threadIdx.x < s) red[threadIdx.x] = fmaxf(red[threadIdx.x], red[threadIdx.x + s]);
        __syncthreads();
    }
    if (threadIdx.x == 0) flag[0] = (red[0] > 1e6f) ? 1 : 0;
}

__global__ __launch_bounds__(256) void convert_kernel(
    const void* __restrict__ src, bf16* __restrict__ dst,
    const int* __restrict__ flag, int n)
{
    int is32 = flag[0];
    int i0 = (blockIdx.x * 256 + threadIdx.x) * 4;
#pragma unroll
    for (int j = 0; j < 4; j++) {
        int i = i0 + j;
        if (i < n)
            dst[i] = is32 ? f2b(((const float*)src)[i]) : ((const bf16*)src)[i];
    }
}

// Transposing convert: W[K][N] (fp32|bf16) -> WT[N][K] bf16. 64x64 LDS tiles.
__global__ __launch_bounds__(256) void convert_t_kernel(
    const void* __restrict__ src, bf16* __restrict__ dst,
    const int* __restrict__ flag, int K, int N)
{
    __shared__ bf16 tile[64 * 72];
    int is32 = flag[0];
    int k0 = blockIdx.y * 64, n0 = blockIdx.x * 64;
    int tid = threadIdx.x;
    int r = tid >> 2, seg = (tid & 3) * 16;
#pragma unroll
    for (int i = 0; i < 16; i++) {
        size_t gi = (size_t)(k0 + r) * N + n0 + seg + i;
        float v = is32 ? ((const float*)src)[gi] : b2f(((const bf16*)src)[gi]);
        tile[r * 72 + seg + i] = f2b(v);
    }
    __syncthreads();
    bf16 tmp[16];
#pragma unroll
    for (int i = 0; i < 16; i++) tmp[i] = tile[(seg + i) * 72 + r];
    size_t o = (size_t)(n0 + r) * K + k0 + seg;
    *(s8v*)&dst[o] = *(s8v*)&tmp[0];
    *(s8v*)&dst[o + 8] = *(s8v*)&tmp[8];
}

// ---------------------------------------------------------------------------
// MFMA GEMM: C[M,N] = A[M,K] * BT[N,K]^T, bf16 in, fp32 acc.
// 128x128 tile, BK=64, 4 waves (each a 64x64 quadrant of 4x4 16x16 frags).
// EP: 0 bf16 out; 2 bf16 exp(clip()) dual-store (E + ET); 3 dynamic fp32/bf16.
// ---------------------------------------------------------------------------
template <int EP>
__global__ __launch_bounds__(256) void gemm_mfma(
    const bf16* __restrict__ A, const bf16* __restrict__ BT,
    void* __restrict__ Cout, bf16* __restrict__ Cout2,
    const int* __restrict__ flag, int M, int N, int K)
{
    __shared__ bf16 Xs[128 * 72];
    __shared__ bf16 Ws[128 * 72];
    const int tid = threadIdx.x;
    const int w = tid >> 6, lane = tid & 63;
    const int l16 = lane & 15, q = lane >> 4;
    const int wr = w >> 1, wc = w & 1;
    const int m0 = blockIdx.y * 128, n0 = blockIdx.x * 128;
    int dyn = 0;
    if (EP == 3) dyn = flag[0];

    f4v acc[4][4];
    f4v z = {0.f, 0.f, 0.f, 0.f};
#pragma unroll
    for (int i = 0; i < 4; i++)
#pragma unroll
        for (int j = 0; j < 4; j++) acc[i][j] = z;

    for (int k0 = 0; k0 < K; k0 += 64) {
#pragma unroll
        for (int c = 0; c < 4; c++) {
            int chunk = c * 256 + tid;
            int r = chunk >> 3, kc = chunk & 7;
            *(s8v*)&Xs[r * 72 + kc * 8] = *(const s8v*)&A[(size_t)(m0 + r) * K + k0 + kc * 8];
            *(s8v*)&Ws[r * 72 + kc * 8] = *(const s8v*)&BT[(size_t)(n0 + r) * K + k0 + kc * 8];
        }
        __syncthreads();
#pragma unroll
        for (int kq = 0; kq < 2; kq++) {
            s8v a[4], b[4];
#pragma unroll
            for (int mi = 0; mi < 4; mi++)
                a[mi] = *(s8v*)&Xs[(wr * 64 + mi * 16 + l16) * 72 + kq * 32 + q * 8];
#pragma unroll
            for (int ni = 0; ni < 4; ni++)
                b[ni] = *(s8v*)&Ws[(wc * 64 + ni * 16 + l16) * 72 + kq * 32 + q * 8];
#pragma unroll
            for (int mi = 0; mi < 4; mi++)
#pragma unroll
                for (int ni = 0; ni < 4; ni++)
                    acc[mi][ni] = mfma16(a[mi], b[ni], acc[mi][ni]);
        }
        __syncthreads();
    }
#pragma unroll
    for (int mi = 0; mi < 4; mi++)
#pragma unroll
        for (int ni = 0; ni < 4; ni++)
#pragma unroll
            for (int r = 0; r < 4; r++) {
                int row = m0 + wr * 64 + mi * 16 + q * 4 + r;
                int col = n0 + wc * 64 + ni * 16 + l16;
                size_t idx = (size_t)row * N + col;
                float v = acc[mi][ni][r];
                if (EP == 2) {
                    float cl = fminf(32.f, fmaxf(-32.f, v));
                    bf16 e = f2b(expf(cl));
                    ((bf16*)Cout)[idx] = e;
                    int b_ = row >> 11, t_ = row & 2047;
                    int h_ = col >> 6, m_ = col & 63;
                    Cout2[((size_t)((b_ * 4 + h_) * 64 + m_)) * 2048 + t_] = e;
                } else if (EP == 3) {
                    if (dyn) ((float*)Cout)[idx] = v;
                    else ((bf16*)Cout)[idx] = f2b(v);
                } else {
                    ((bf16*)Cout)[idx] = f2b(v);
                }
            }
}

// ---------------------------------------------------------------------------
// Depthwise causal conv (KS=4) + SiLU + RoPE for q/k (bf16 pre, C=512).
// ---------------------------------------------------------------------------
__global__ __launch_bounds__(256) void conv_qk_rope_kernel(
    const bf16* __restrict__ pre, const bf16* __restrict__ w,
    bf16* __restrict__ out)
{
    int gid = blockIdx.x * 256 + threadIdx.x;  // B*T*H*64
    int d = gid & 63;
    int h = (gid >> 6) & 3;
    int t = (gid >> 8) & 2047;
    int b = gid >> 19;
    int clo = h * HKn + d, chi = clo + 64;
    float ylo = 0.f, yhi = 0.f;
#pragma unroll
    for (int j = 0; j < 4; j++) {
        int tt = t - 3 + j;
        if (tt >= 0) {
            size_t rb = (size_t)(b * Tn + tt) * KDn;
            ylo += b2f(pre[rb + clo]) * b2f(w[clo * 4 + j]);
            yhi += b2f(pre[rb + chi]) * b2f(w[chi * 4 + j]);
        }
    }
    ylo = ylo / (1.f + expf(-ylo));
    yhi = yhi / (1.f + expf(-yhi));
    float invf = powf(10000.f, -(float)d * (1.f / 64.f));
    float th = (float)t * invf;
    float c = cosf(th), s = sinf(th);
    size_t rowbase = (size_t)(b * Tn + t) * KDn;
    out[rowbase + clo] = f2b(ylo * c - yhi * s);
    out[rowbase + chi] = f2b(yhi * c + ylo * s);
}

// ---------------------------------------------------------------------------
// conv + silu for v, writing V TRANSPOSED: VT[b*1024 + c][t]. 64x64 tiles.
// ---------------------------------------------------------------------------
__global__ __launch_bounds__(256) void conv_v_t_kernel(
    const bf16* __restrict__ pre, const bf16* __restrict__ w,
    bf16* __restrict__ VT)
{
    __shared__ bf16 tile[64 * 72];
    int c0 = blockIdx.x * 64, t0 = blockIdx.y * 64, b = blockIdx.z;
    int tid = threadIdx.x;
    int row = tid >> 2, seg = (tid & 3) * 16;   // row = t-local, seg = c-chunk
    float y[16];
#pragma unroll
    for (int i = 0; i < 16; i++) y[i] = 0.f;
#pragma unroll
    for (int j = 0; j < 4; j++) {
        int tt = t0 + row - 3 + j;
        if (tt >= 0) {
            const bf16* p = &pre[(size_t)(b * Tn + tt) * VDn + c0 + seg];
#pragma unroll
            for (int i = 0; i < 16; i++)
                y[i] += b2f(p[i]) * b2f(w[(c0 + seg + i) * 4 + j]);
        }
    }
#pragma unroll
    for (int i = 0; i < 16; i++) {
        float v = y[i] / (1.f + expf(-y[i]));
        tile[row * 72 + seg + i] = f2b(v);
    }
    __syncthreads();
    // row = c-local now, seg = t-chunk
    bf16 tmp[16];
#pragma unroll
    for (int i = 0; i < 16; i++) tmp[i] = tile[(seg + i) * 72 + row];
    size_t o = (size_t)(b * 1024 + c0 + row) * 2048 + t0 + seg;
    *(s8v*)&VT[o] = *(s8v*)&tmp[0];
    *(s8v*)&VT[o + 8] = *(s8v*)&tmp[8];
}

// ---------------------------------------------------------------------------
// cumsum over tau per (b,h,m) row of ET (contiguous), wave-parallel scan.
// Writes C fp32 in [b][t][hm] layout.
// ---------------------------------------------------------------------------
__global__ __launch_bounds__(256) void cumsum_kernel(
    const bf16* __restrict__ ET, float* __restrict__ C)
{
    int row = blockIdx.x * 4 + (threadIdx.x >> 6);   // 1024 rows
    int lane = threadIdx.x & 63;
    int b = row >> 8, hm = row & 255;
    const bf16* src = ET + (size_t)row * 2048;
    float run = 0.f;
    for (int ch = 0; ch < 32; ch++) {
        float v = b2f(src[ch * 64 + lane]);
#pragma unroll
        for (int off = 1; off < 64; off <<= 1) {
            float o = __shfl_up(v, off, 64);
            if (lane >= off) v += o;
        }
        C[(size_t)(b * 2048 + ch * 64 + lane) * 256 + hm] = run + v;
        run += __shfl(v, 63, 64);
    }
}

// ---------------------------------------------------------------------------
// attn1 (MFMA): per block: 64 t-rows of okT = (S*E)^T, then softmax -> U.
// S = Q K^T (k=128, masked, scaled, ->LDS bf16), okT += ET_frag * S^T.
// ---------------------------------------------------------------------------
__global__ __launch_bounds__(256) void attn1_mfma(
    const bf16* __restrict__ Q, const bf16* __restrict__ K,
    const bf16* __restrict__ ET, const float* __restrict__ C,
    bf16* __restrict__ U)
{
    __shared__ bf16 Sl[64 * 72];
    __shared__ float okT[64 * 65];
    const int tid = threadIdx.x;
    const int w = tid >> 6, lane = tid & 63;
    const int l16 = lane & 15, q = lane >> 4;
    const int t0 = (int)(gridDim.x - 1 - blockIdx.x) * 64;
    const int b = blockIdx.y >> 2, h = blockIdx.y & 3;
    f4v z = {0.f, 0.f, 0.f, 0.f};

    const bf16* qrow = Q + (size_t)(b * Tn + t0 + w * 16 + l16) * KDn + h * HKn;
    s8v qa[4];
#pragma unroll
    for (int kc = 0; kc < 4; kc++) qa[kc] = *(const s8v*)(qrow + kc * 32 + q * 8);
    const bf16* etrow = ET + (size_t)((b * 4 + h) * 64 + w * 16 + l16) * 2048;

    f4v ok[4];
#pragma unroll
    for (int i = 0; i < 4; i++) ok[i] = z;

    for (int tau0 = 0; tau0 <= t0; tau0 += 64) {
        f4v s[4];
#pragma unroll
        for (int fi = 0; fi < 4; fi++) s[fi] = z;
#pragma unroll
        for (int kc = 0; kc < 4; kc++) {
#pragma unroll
            for (int fi = 0; fi < 4; fi++) {
                s8v kb = *(const s8v*)(K + (size_t)(b * Tn + tau0 + fi * 16 + l16) * KDn
                                       + h * HKn + kc * 32 + q * 8);
                s[fi] = mfma16(qa[kc], kb, s[fi]);
            }
        }
        __syncthreads();
#pragma unroll
        for (int fi = 0; fi < 4; fi++)
#pragma unroll
            for (int r = 0; r < 4; r++) {
                int tl = w * 16 + q * 4 + r, cl = fi * 16 + l16;
                float v = s[fi][r] * 0.08838834764831845f;
                Sl[tl * 72 + cl] = ((tau0 + cl) <= (t0 + tl)) ? f2b(v) : f2b(0.f);
            }
        __syncthreads();
#pragma unroll
        for (int kc = 0; kc < 2; kc++) {
            s8v ea = *(const s8v*)(etrow + tau0 + kc * 32 + q * 8);
#pragma unroll
            for (int tf = 0; tf < 4; tf++) {
                s8v sb = *(s8v*)&Sl[(tf * 16 + l16) * 72 + kc * 32 + q * 8];
                ok[tf] = mfma16(ea, sb, ok[tf]);
            }
        }
    }
    __syncthreads();
#pragma unroll
    for (int tf = 0; tf < 4; tf++)
#pragma unroll
        for (int r = 0; r < 4; r++)
            okT[(w * 16 + q * 4 + r) * 65 + tf * 16 + l16] = ok[tf][r];
    __syncthreads();
    if (tid < 64) {
        int t = tid;
        size_t base = (size_t)(b * Tn + t0 + t) * 256 + h * 64;
        float mx = -1e30f;
        for (int m = 0; m < 64; m++) {
            float v = okT[m * 65 + t] / C[base + m];
            okT[m * 65 + t] = v;
            mx = fmaxf(mx, v);
        }
        float sum = 0.f;
        for (int m = 0; m < 64; m++) {
            float e = expf(okT[m * 65 + t] - mx);
            okT[m * 65 + t] = e;
            sum += e;
        }
        float inv = 1.f / sum;
        for (int m = 0; m < 64; m++)
            U[base + m] = f2b(okT[m * 65 + t] * inv / C[base + m]);
    }
}

// ---------------------------------------------------------------------------
// attn2 (MFMA): per block 64 t x 64 v. P = U E^T (masked -> LDS bf16),
// O^T += VT_frag * P^T. grid (32 rev, 16 bh, 4 vchunk).
// ---------------------------------------------------------------------------
__global__ __launch_bounds__(256) void attn2_mfma(
    const bf16* __restrict__ U, const bf16* __restrict__ E,
    const bf16* __restrict__ VT, bf16* __restrict__ OV)
{
    __shared__ bf16 Pl[64 * 72];
    __shared__ float Ot[64 * 65];
    const int tid = threadIdx.x;
    const int w = tid >> 6, lane = tid & 63;
    const int l16 = lane & 15, q = lane >> 4;
    const int t0 = (int)(gridDim.x - 1 - blockIdx.x) * 64;
    const int b = blockIdx.y >> 2, h = blockIdx.y & 3;
    const int zc = blockIdx.z;
    f4v z = {0.f, 0.f, 0.f, 0.f};

    const bf16* urow = U + (size_t)(b * Tn + t0 + w * 16 + l16) * 256 + h * 64;
    s8v ua[2];
#pragma unroll
    for (int kc = 0; kc < 2; kc++) ua[kc] = *(const s8v*)(urow + kc * 32 + q * 8);
    const bf16* vtrow = VT + (size_t)(b * 1024 + h * 256 + zc * 64 + w * 16 + l16) * 2048;

    f4v oacc[4];
#pragma unroll
    for (int i = 0; i < 4; i++) oacc[i] = z;

    for (int tau0 = 0; tau0 <= t0; tau0 += 64) {
        f4v p[4];
#pragma unroll
        for (int fi = 0; fi < 4; fi++) p[fi] = z;
#pragma unroll
        for (int kc = 0; kc < 2; kc++) {
#pragma unroll
            for (int fi = 0; fi < 4; fi++) {
                s8v eb = *(const s8v*)(E + (size_t)(b * Tn + tau0 + fi * 16 + l16) * 256
                                       + h * 64 + kc * 32 + q * 8);
                p[fi] = mfma16(ua[kc], eb, p[fi]);
            }
        }
        __syncthreads();
#pragma unroll
        for (int fi = 0; fi < 4; fi++)
#pragma unroll
            for (int r = 0; r < 4; r++) {
                int tl = w * 16 + q * 4 + r, cl = fi * 16 + l16;
                Pl[tl * 72 + cl] = ((tau0 + cl) <= (t0 + tl)) ? f2b(p[fi][r]) : f2b(0.f);
            }
        __syncthreads();
#pragma unroll
        for (int kc = 0; kc < 2; kc++) {
            s8v va = *(const s8v*)(vtrow + tau0 + kc * 32 + q * 8);
#pragma unroll
            for (int tf = 0; tf < 4; tf++) {
                s8v pb = *(s8v*)&Pl[(tf * 16 + l16) * 72 + kc * 32 + q * 8];
                oacc[tf] = mfma16(va, pb, oacc[tf]);
            }
        }
    }
    __syncthreads();
#pragma unroll
    for (int tf = 0; tf < 4; tf++)
#pragma unroll
        for (int r = 0; r < 4; r++)
            Ot[(w * 16 + q * 4 + r) * 65 + tf * 16 + l16] = oacc[tf][r];
    __syncthreads();
    int trow = tid >> 2, vseg = (tid & 3) * 16;
    bf16 tmp[16];
#pragma unroll
    for (int i = 0; i < 16; i++) tmp[i] = f2b(Ot[(vseg + i) * 65 + trow]);
    size_t o = (size_t)(b * Tn + t0 + trow) * VDn + h * HVn + zc * 64 + vseg;
    *(s8v*)&OV[o] = *(s8v*)&tmp[0];
    *(s8v*)&OV[o + 8] = *(s8v*)&tmp[8];
}

// ---------------------------------------------------------------------------
// Per-(b,t,h) RMS norm over hv=256, * gnorm_w * silu(g). IN-PLACE on OV.
// ---------------------------------------------------------------------------
__global__ __launch_bounds__(256) void norm_gate_kernel(
    bf16* __restrict__ OV, const bf16* __restrict__ G,
    const bf16* __restrict__ gn)
{
    int gid = blockIdx.x;            // B*T*H = 32768
    int h = gid & 3;
    int t = (gid >> 2) & 2047;
    int b = gid >> 13;
    int v = threadIdx.x;
    size_t idx = (size_t)(b * Tn + t) * VDn + h * HVn + v;
    float val = b2f(OV[idx]);
    float ss = val * val;
#pragma unroll
    for (int off = 32; off > 0; off >>= 1) ss += __shfl_down(ss, off, 64);
    __shared__ float red[4];
    int lane = threadIdx.x & 63, wid = threadIdx.x >> 6;
    if (lane == 0) red[wid] = ss;
    __syncthreads();
    float tot = red[0] + red[1] + red[2] + red[3];
    float rs = rsqrtf(tot * (1.0f / 256.0f) + 1e-5f);
    float g = b2f(G[idx]);
    float sg = g / (1.f + expf(-g));
    OV[idx] = f2b(val * rs * b2f(gn[v]) * sg);
}

// ---------------------------------------------------------------------------
extern "C" void kernel_launch(void* const* d_in, const int* in_sizes, int n_in,
                              void* d_out, int out_size, void* d_ws, size_t ws_size,
                              hipStream_t stream)
{
    constexpr size_t MB = 1u << 20;
    char* w = (char*)d_ws;
    bf16* Xb   = (bf16*)(w + 0);               // [0,16)
    bf16* WoT  = (bf16*)(w + 16 * MB);         // [16,18)
    bf16* gnwb = (bf16*)(w + 18 * MB);
    bf16* qwb  = (bf16*)(w + 18 * MB + 4096);
    bf16* kwb  = (bf16*)(w + 18 * MB + 8192);
    bf16* vwb  = (bf16*)(w + 18 * MB + 16384);
    bf16* WqT  = (bf16*)(w + 19 * MB);         // [19,20)
    bf16* WkT  = (bf16*)(w + 20 * MB);         // [20,21)
    bf16* WvT  = (bf16*)(w + 21 * MB);         // [21,23)
    bf16* WsT  = (bf16*)(w + 23 * MB);         // [23,23.5)
    bf16* WgT  = (bf16*)(w + 24 * MB);         // [24,26)
    bf16* preB = (bf16*)(w + 26 * MB);         // [26,42) pre-activations
    bf16* Ebuf = (bf16*)(w + 26 * MB);         // [26,30) after convs
    bf16* ETb  = (bf16*)(w + 30 * MB);         // [30,34)
    float* Cbuf = (float*)(w + 34 * MB);       // [34,42)
    bf16* ghat = (bf16*)(w + 26 * MB);         // [26,42) after attn2
    bf16* Qb   = (bf16*)(w + 42 * MB);         // [42,50)
    bf16* Kb   = (bf16*)(w + 50 * MB);         // [50,58)
    bf16* OVb  = (bf16*)(w + 42 * MB);         // [42,58) after attn1
    bf16* Ubuf = (bf16*)(w + 58 * MB);         // [58,62)
    int*  flagp = (int*)(w + 62 * MB);
    bf16* VT   = (bf16*)d_out;                 // V^T staged in d_out

    dim3 blk(256);
    probe_dtype_kernel<<<1, blk, 0, stream>>>(d_in[0], flagp);
    convert_kernel<<<8192, blk, 0, stream>>>(d_in[0], Xb, flagp, BT * Dn);
    convert_t_kernel<<<dim3(KDn / 64, Dn / 64), blk, 0, stream>>>(d_in[1], WqT, flagp, Dn, KDn);
    convert_t_kernel<<<dim3(KDn / 64, Dn / 64), blk, 0, stream>>>(d_in[2], WkT, flagp, Dn, KDn);
    convert_t_kernel<<<dim3(VDn / 64, Dn / 64), blk, 0, stream>>>(d_in[3], WvT, flagp, Dn, VDn);
    convert_t_kernel<<<dim3(256 / 64, Dn / 64), blk, 0, stream>>>(d_in[4], WsT, flagp, Dn, 256);
    convert_t_kernel<<<dim3(VDn / 64, Dn / 64), blk, 0, stream>>>(d_in[5], WgT, flagp, Dn, VDn);
    convert_t_kernel<<<dim3(Dn / 64, VDn / 64), blk, 0, stream>>>(d_in[6], WoT, flagp, VDn, Dn);
    convert_kernel<<<2, blk, 0, stream>>>(d_in[7], qwb, flagp, KDn * 4);
    convert_kernel<<<2, blk, 0, stream>>>(d_in[8], kwb, flagp, KDn * 4);
    convert_kernel<<<4, blk, 0, stream>>>(d_in[9], vwb, flagp, VDn * 4);
    convert_kernel<<<1, blk, 0, stream>>>(d_in[10], gnwb, flagp, HVn);
    // q path
    gemm_mfma<0><<<dim3(4, 64), blk, 0, stream>>>(Xb, WqT, preB, nullptr, flagp, BT, KDn, Dn);
    conv_qk_rope_kernel<<<8192, blk, 0, stream>>>(preB, qwb, Qb);
    // k path
    gemm_mfma<0><<<dim3(4, 64), blk, 0, stream>>>(Xb, WkT, preB, nullptr, flagp, BT, KDn, Dn);
    conv_qk_rope_kernel<<<8192, blk, 0, stream>>>(preB, kwb, Kb);
    // v path -> VT in d_out
    gemm_mfma<0><<<dim3(8, 64), blk, 0, stream>>>(Xb, WvT, preB, nullptr, flagp, BT, VDn, Dn);
    conv_v_t_kernel<<<dim3(16, 32, 4), blk, 0, stream>>>(preB, vwb, VT);
    // slot gates: E (and ET) = exp(clip(X@Ws)); C = cumsum(ET)
    gemm_mfma<2><<<dim3(2, 64), blk, 0, stream>>>(Xb, WsT, Ebuf, ETb, flagp, BT, 256, Dn);
    cumsum_kernel<<<256, blk, 0, stream>>>(ETb, Cbuf);
    // attention-form passes
    attn1_mfma<<<dim3(32, 16), blk, 0, stream>>>(Qb, Kb, ETb, Cbuf, Ubuf);
    attn2_mfma<<<dim3(32, 16, 4), blk, 0, stream>>>(Ubuf, Ebuf, VT, OVb);
    // gate projection + norm
    gemm_mfma<0><<<dim3(8, 64), blk, 0, stream>>>(Xb, WgT, ghat, nullptr, flagp, BT, VDn, Dn);
    norm_gate_kernel<<<32768, blk, 0, stream>>>(OVb, ghat, gnwb);
    // output projection
    gemm_mfma<3><<<dim3(8, 64), blk, 0, stream>>>(OVb, WoT, d_out, nullptr, flagp, BT, Dn, VDn);
}

// Round 5
// 497.535 us; speedup vs baseline: 10.1391x; 1.7703x over previous
//
#include <hip/hip_runtime.h>
#include <hip/hip_bf16.h>
#include <math.h>

typedef __hip_bfloat16 bf16;
typedef short s8v __attribute__((ext_vector_type(8)));
typedef float f4v __attribute__((ext_vector_type(4)));

__device__ __forceinline__ float b2f(bf16 x) { return __bfloat162float(x); }
__device__ __forceinline__ bf16 f2b(float x) { return __float2bfloat16(x); }
__device__ __forceinline__ f4v mfma16(s8v a, s8v b, f4v c) {
    return __builtin_amdgcn_mfma_f32_16x16x32_bf16(a, b, c, 0, 0, 0);
}

// Problem constants
constexpr int Bn = 4, Tn = 2048, Dn = 1024, KDn = 512, VDn = 1024;
constexpr int Hn = 4, Mn = 64, HKn = 128, HVn = 256;
constexpr int BT = Bn * Tn; // 8192

// ---------------------------------------------------------------------------
// Dtype probe (fp32 vs bf16 inputs).
// ---------------------------------------------------------------------------
__global__ __launch_bounds__(256) void probe_dtype_kernel(
    const void* __restrict__ x, int* __restrict__ flag)
{
    const bf16* xb = (const bf16*)x;
    float mx = 0.f;
    for (int i = threadIdx.x; i < 4096; i += 256) {
        float v = fabsf(b2f(xb[i]));
        if (isnan(v)) v = 1e30f;
        mx = fmaxf(mx, v);
    }
    __shared__ float red[256];
    red[threadIdx.x] = mx;
    __syncthreads();
    for (int s = 128; s > 0; s >>= 1) {
        if (threadIdx.x < s) red[threadIdx.x] = fmaxf(red[threadIdx.x], red[threadIdx.x + s]);
        __syncthreads();
    }
    if (threadIdx.x == 0) flag[0] = (red[0] > 1e6f) ? 1 : 0;
}

__global__ __launch_bounds__(256) void convert_kernel(
    const void* __restrict__ src, bf16* __restrict__ dst,
    const int* __restrict__ flag, int n)
{
    int is32 = flag[0];
    int i0 = (blockIdx.x * 256 + threadIdx.x) * 4;
#pragma unroll
    for (int j = 0; j < 4; j++) {
        int i = i0 + j;
        if (i < n)
            dst[i] = is32 ? f2b(((const float*)src)[i]) : ((const bf16*)src)[i];
    }
}

// Transposing convert: W[K][N] (fp32|bf16) -> WT[N][K] bf16. 64x64 LDS tiles.
__global__ __launch_bounds__(256) void convert_t_kernel(
    const void* __restrict__ src, bf16* __restrict__ dst,
    const int* __restrict__ flag, int K, int N)
{
    __shared__ bf16 tile[64 * 72];
    int is32 = flag[0];
    int k0 = blockIdx.y * 64, n0 = blockIdx.x * 64;
    int tid = threadIdx.x;
    int r = tid >> 2, seg = (tid & 3) * 16;
#pragma unroll
    for (int i = 0; i < 16; i++) {
        size_t gi = (size_t)(k0 + r) * N + n0 + seg + i;
        float v = is32 ? ((const float*)src)[gi] : b2f(((const bf16*)src)[gi]);
        tile[r * 72 + seg + i] = f2b(v);
    }
    __syncthreads();
    bf16 tmp[16];
#pragma unroll
    for (int i = 0; i < 16; i++) tmp[i] = tile[(seg + i) * 72 + r];
    size_t o = (size_t)(n0 + r) * K + k0 + seg;
    *(s8v*)&dst[o] = *(s8v*)&tmp[0];
    *(s8v*)&dst[o + 8] = *(s8v*)&tmp[8];
}

// ---------------------------------------------------------------------------
// MFMA GEMM: C[M,N] = A[M,K] * BT[N,K]^T, bf16 in, fp32 acc.
// 128x128 tile, BK=64, 4 waves. EP: 0 bf16; 2 exp-clip dual-store; 3 dynamic.
// ---------------------------------------------------------------------------
template <int EP>
__global__ __launch_bounds__(256) void gemm_mfma(
    const bf16* __restrict__ A, const bf16* __restrict__ BT,
    void* __restrict__ Cout, bf16* __restrict__ Cout2,
    const int* __restrict__ flag, int M, int N, int K)
{
    __shared__ bf16 Xs[128 * 72];
    __shared__ bf16 Ws[128 * 72];
    const int tid = threadIdx.x;
    const int w = tid >> 6, lane = tid & 63;
    const int l16 = lane & 15, q = lane >> 4;
    const int wr = w >> 1, wc = w & 1;
    const int m0 = blockIdx.y * 128, n0 = blockIdx.x * 128;
    int dyn = 0;
    if (EP == 3) dyn = flag[0];

    f4v acc[4][4];
    f4v z = {0.f, 0.f, 0.f, 0.f};
#pragma unroll
    for (int i = 0; i < 4; i++)
#pragma unroll
        for (int j = 0; j < 4; j++) acc[i][j] = z;

    for (int k0 = 0; k0 < K; k0 += 64) {
#pragma unroll
        for (int c = 0; c < 4; c++) {
            int chunk = c * 256 + tid;
            int r = chunk >> 3, kc = chunk & 7;
            *(s8v*)&Xs[r * 72 + kc * 8] = *(const s8v*)&A[(size_t)(m0 + r) * K + k0 + kc * 8];
            *(s8v*)&Ws[r * 72 + kc * 8] = *(const s8v*)&BT[(size_t)(n0 + r) * K + k0 + kc * 8];
        }
        __syncthreads();
#pragma unroll
        for (int kq = 0; kq < 2; kq++) {
            s8v a[4], b[4];
#pragma unroll
            for (int mi = 0; mi < 4; mi++)
                a[mi] = *(s8v*)&Xs[(wr * 64 + mi * 16 + l16) * 72 + kq * 32 + q * 8];
#pragma unroll
            for (int ni = 0; ni < 4; ni++)
                b[ni] = *(s8v*)&Ws[(wc * 64 + ni * 16 + l16) * 72 + kq * 32 + q * 8];
#pragma unroll
            for (int mi = 0; mi < 4; mi++)
#pragma unroll
                for (int ni = 0; ni < 4; ni++)
                    acc[mi][ni] = mfma16(a[mi], b[ni], acc[mi][ni]);
        }
        __syncthreads();
    }
#pragma unroll
    for (int mi = 0; mi < 4; mi++)
#pragma unroll
        for (int ni = 0; ni < 4; ni++)
#pragma unroll
            for (int r = 0; r < 4; r++) {
                int row = m0 + wr * 64 + mi * 16 + q * 4 + r;
                int col = n0 + wc * 64 + ni * 16 + l16;
                size_t idx = (size_t)row * N + col;
                float v = acc[mi][ni][r];
                if (EP == 2) {
                    float cl = fminf(32.f, fmaxf(-32.f, v));
                    bf16 e = f2b(expf(cl));
                    ((bf16*)Cout)[idx] = e;
                    int b_ = row >> 11, t_ = row & 2047;
                    int h_ = col >> 6, m_ = col & 63;
                    Cout2[((size_t)((b_ * 4 + h_) * 64 + m_)) * 2048 + t_] = e;
                } else if (EP == 3) {
                    if (dyn) ((float*)Cout)[idx] = v;
                    else ((bf16*)Cout)[idx] = f2b(v);
                } else {
                    ((bf16*)Cout)[idx] = f2b(v);
                }
            }
}

// ---------------------------------------------------------------------------
// Depthwise causal conv (KS=4) + SiLU + RoPE for q/k (bf16 pre, C=512).
// ---------------------------------------------------------------------------
__global__ __launch_bounds__(256) void conv_qk_rope_kernel(
    const bf16* __restrict__ pre, const bf16* __restrict__ w,
    bf16* __restrict__ out)
{
    int gid = blockIdx.x * 256 + threadIdx.x;  // B*T*H*64
    int d = gid & 63;
    int h = (gid >> 6) & 3;
    int t = (gid >> 8) & 2047;
    int b = gid >> 19;
    int clo = h * HKn + d, chi = clo + 64;
    float ylo = 0.f, yhi = 0.f;
#pragma unroll
    for (int j = 0; j < 4; j++) {
        int tt = t - 3 + j;
        if (tt >= 0) {
            size_t rb = (size_t)(b * Tn + tt) * KDn;
            ylo += b2f(pre[rb + clo]) * b2f(w[clo * 4 + j]);
            yhi += b2f(pre[rb + chi]) * b2f(w[chi * 4 + j]);
        }
    }
    ylo = ylo / (1.f + expf(-ylo));
    yhi = yhi / (1.f + expf(-yhi));
    float invf = powf(10000.f, -(float)d * (1.f / 64.f));
    float th = (float)t * invf;
    float c = cosf(th), s = sinf(th);
    size_t rowbase = (size_t)(b * Tn + t) * KDn;
    out[rowbase + clo] = f2b(ylo * c - yhi * s);
    out[rowbase + chi] = f2b(yhi * c + ylo * s);
}

// ---------------------------------------------------------------------------
// conv + silu for v, writing V TRANSPOSED: VT[b*1024 + c][t]. 64x64 tiles.
// ---------------------------------------------------------------------------
__global__ __launch_bounds__(256) void conv_v_t_kernel(
    const bf16* __restrict__ pre, const bf16* __restrict__ w,
    bf16* __restrict__ VT)
{
    __shared__ bf16 tile[64 * 72];
    int c0 = blockIdx.x * 64, t0 = blockIdx.y * 64, b = blockIdx.z;
    int tid = threadIdx.x;
    int row = tid >> 2, seg = (tid & 3) * 16;
    float y[16];
#pragma unroll
    for (int i = 0; i < 16; i++) y[i] = 0.f;
#pragma unroll
    for (int j = 0; j < 4; j++) {
        int tt = t0 + row - 3 + j;
        if (tt >= 0) {
            const bf16* p = &pre[(size_t)(b * Tn + tt) * VDn + c0 + seg];
#pragma unroll
            for (int i = 0; i < 16; i++)
                y[i] += b2f(p[i]) * b2f(w[(c0 + seg + i) * 4 + j]);
        }
    }
#pragma unroll
    for (int i = 0; i < 16; i++) {
        float v = y[i] / (1.f + expf(-y[i]));
        tile[row * 72 + seg + i] = f2b(v);
    }
    __syncthreads();
    bf16 tmp[16];
#pragma unroll
    for (int i = 0; i < 16; i++) tmp[i] = tile[(seg + i) * 72 + row];
    size_t o = (size_t)(b * 1024 + c0 + row) * 2048 + t0 + seg;
    *(s8v*)&VT[o] = *(s8v*)&tmp[0];
    *(s8v*)&VT[o + 8] = *(s8v*)&tmp[8];
}

// ---------------------------------------------------------------------------
// cumsum over tau per (b,h,m) row of ET; wave-parallel scan. C fp32 [b][t][hm].
// ---------------------------------------------------------------------------
__global__ __launch_bounds__(256) void cumsum_kernel(
    const bf16* __restrict__ ET, float* __restrict__ C)
{
    int row = blockIdx.x * 4 + (threadIdx.x >> 6);   // 1024 rows
    int lane = threadIdx.x & 63;
    int b = row >> 8, hm = row & 255;
    const bf16* src = ET + (size_t)row * 2048;
    float run = 0.f;
    for (int ch = 0; ch < 32; ch++) {
        float v = b2f(src[ch * 64 + lane]);
#pragma unroll
        for (int off = 1; off < 64; off <<= 1) {
            float o = __shfl_up(v, off, 64);
            if (lane >= off) v += o;
        }
        C[(size_t)(b * 2048 + ch * 64 + lane) * 256 + hm] = run + v;
        run += __shfl(v, 63, 64);
    }
}

// ---------------------------------------------------------------------------
// attn1 (MFMA): S = Q K^T (K staged in LDS w/ reg-prefetch), masked->Sl,
// okT += ET * S^T, softmax -> U.  grid (bh=16, ttile=32 reversed).
// ---------------------------------------------------------------------------
__global__ __launch_bounds__(256) void attn1_mfma(
    const bf16* __restrict__ Q, const bf16* __restrict__ K,
    const bf16* __restrict__ ET, const float* __restrict__ C,
    bf16* __restrict__ U)
{
    __shared__ bf16 Kl[64 * 136];
    __shared__ bf16 Sl[64 * 72];
    __shared__ float okT[64 * 65];
    const int tid = threadIdx.x;
    const int w = tid >> 6, lane = tid & 63;
    const int l16 = lane & 15, q = lane >> 4;
    const int b = blockIdx.x >> 2, h = blockIdx.x & 3;
    const int t0 = (int)(gridDim.y - 1 - blockIdx.y) * 64;
    f4v z = {0.f, 0.f, 0.f, 0.f};

    const bf16* qrow = Q + (size_t)(b * Tn + t0 + w * 16 + l16) * KDn + h * HKn;
    s8v qa[4];
#pragma unroll
    for (int kc = 0; kc < 4; kc++) qa[kc] = *(const s8v*)(qrow + kc * 32 + q * 8);
    const bf16* etrow = ET + (size_t)((b * 4 + h) * 64 + w * 16 + l16) * 2048;
    // K staging address pattern (per thread): 4 chunks of s8v
    const int krow[4] = {(0 * 256 + tid) >> 4, (1 * 256 + tid) >> 4,
                         (2 * 256 + tid) >> 4, (3 * 256 + tid) >> 4};
    const int kcol = (tid & 15) * 8;
    const bf16* kbase = K + (size_t)b * Tn * KDn + h * HKn;

    f4v ok[4];
#pragma unroll
    for (int i = 0; i < 4; i++) ok[i] = z;

    // prefetch K regs for first iter
    s8v kreg[4];
#pragma unroll
    for (int c = 0; c < 4; c++)
        kreg[c] = *(const s8v*)(kbase + (size_t)(0 + krow[c]) * KDn + kcol);

    for (int tau0 = 0; tau0 <= t0; tau0 += 64) {
        // ET frags for this iter (consumed at the end)
        s8v ea[2];
#pragma unroll
        for (int kc = 0; kc < 2; kc++) ea[kc] = *(const s8v*)(etrow + tau0 + kc * 32 + q * 8);
        __syncthreads();                       // prev readers of Kl/Sl done
#pragma unroll
        for (int c = 0; c < 4; c++)
            *(s8v*)&Kl[krow[c] * 136 + kcol] = kreg[c];
        if (tau0 + 64 <= t0) {
#pragma unroll
            for (int c = 0; c < 4; c++)
                kreg[c] = *(const s8v*)(kbase + (size_t)(tau0 + 64 + krow[c]) * KDn + kcol);
        }
        __syncthreads();                       // Kl ready
        f4v s[4];
#pragma unroll
        for (int fi = 0; fi < 4; fi++) s[fi] = z;
#pragma unroll
        for (int kc = 0; kc < 4; kc++)
#pragma unroll
            for (int fi = 0; fi < 4; fi++) {
                s8v kb = *(s8v*)&Kl[(fi * 16 + l16) * 136 + kc * 32 + q * 8];
                s[fi] = mfma16(qa[kc], kb, s[fi]);
            }
#pragma unroll
        for (int fi = 0; fi < 4; fi++)
#pragma unroll
            for (int r = 0; r < 4; r++) {
                int tl = w * 16 + q * 4 + r, cl = fi * 16 + l16;
                float v = s[fi][r] * 0.08838834764831845f;
                Sl[tl * 72 + cl] = ((tau0 + cl) <= (t0 + tl)) ? f2b(v) : f2b(0.f);
            }
        __syncthreads();                       // Sl ready
#pragma unroll
        for (int kc = 0; kc < 2; kc++)
#pragma unroll
            for (int tf = 0; tf < 4; tf++) {
                s8v sb = *(s8v*)&Sl[(tf * 16 + l16) * 72 + kc * 32 + q * 8];
                ok[tf] = mfma16(ea[kc], sb, ok[tf]);
            }
    }
    __syncthreads();
#pragma unroll
    for (int tf = 0; tf < 4; tf++)
#pragma unroll
        for (int r = 0; r < 4; r++)
            okT[(w * 16 + q * 4 + r) * 65 + tf * 16 + l16] = ok[tf][r];
    __syncthreads();
    if (tid < 64) {
        int t = tid;
        size_t base = (size_t)(b * Tn + t0 + t) * 256 + h * 64;
        float mx = -1e30f;
        for (int m = 0; m < 64; m++) {
            float v = okT[m * 65 + t] / C[base + m];
            okT[m * 65 + t] = v;
            mx = fmaxf(mx, v);
        }
        float sum = 0.f;
        for (int m = 0; m < 64; m++) {
            float e = expf(okT[m * 65 + t] - mx);
            okT[m * 65 + t] = e;
            sum += e;
        }
        float inv = 1.f / sum;
        for (int m = 0; m < 64; m++)
            U[base + m] = f2b(okT[m * 65 + t] * inv / C[base + m]);
    }
}

// ---------------------------------------------------------------------------
// attn2 (MFMA): per block 64 t x 256 v (all zc). P = U E^T once per tau-tile
// (E staged in LDS w/ reg-prefetch), O^T += VT * P^T for 4 v-chunks.
// grid (bh=16, ttile=32 reversed).
// ---------------------------------------------------------------------------
__global__ __launch_bounds__(256) void attn2_mfma(
    const bf16* __restrict__ U, const bf16* __restrict__ E,
    const bf16* __restrict__ VT, bf16* __restrict__ OV)
{
    __shared__ bf16 El[64 * 72];
    __shared__ bf16 Pl[64 * 72];
    __shared__ float Ot[64 * 65];
    const int tid = threadIdx.x;
    const int w = tid >> 6, lane = tid & 63;
    const int l16 = lane & 15, q = lane >> 4;
    const int b = blockIdx.x >> 2, h = blockIdx.x & 3;
    const int t0 = (int)(gridDim.y - 1 - blockIdx.y) * 64;
    f4v z = {0.f, 0.f, 0.f, 0.f};

    const bf16* urow = U + (size_t)(b * Tn + t0 + w * 16 + l16) * 256 + h * 64;
    s8v ua[2];
#pragma unroll
    for (int kc = 0; kc < 2; kc++) ua[kc] = *(const s8v*)(urow + kc * 32 + q * 8);
    const bf16* ebase = E + (size_t)b * Tn * 256 + h * 64;
    // E staging pattern: 2 chunks per thread
    const int erow[2] = {(0 * 256 + tid) >> 3, (1 * 256 + tid) >> 3};
    const int ecol = (tid & 7) * 8;
    const bf16* vtbase = VT + (size_t)(b * 1024 + h * 256 + w * 16 + l16) * 2048;

    f4v oacc[4][4];
#pragma unroll
    for (int zc = 0; zc < 4; zc++)
#pragma unroll
        for (int i = 0; i < 4; i++) oacc[zc][i] = z;

    s8v ereg[2];
#pragma unroll
    for (int c = 0; c < 2; c++)
        ereg[c] = *(const s8v*)(ebase + (size_t)(0 + erow[c]) * 256 + ecol);

    for (int tau0 = 0; tau0 <= t0; tau0 += 64) {
        // VT frags for this iter (consumed in O-phase after 2 barriers)
        s8v vt[4][2];
#pragma unroll
        for (int zc = 0; zc < 4; zc++)
#pragma unroll
            for (int kc = 0; kc < 2; kc++)
                vt[zc][kc] = *(const s8v*)(vtbase + (size_t)(zc * 64) * 2048
                                           + tau0 + kc * 32 + q * 8);
        __syncthreads();                       // prev readers of El/Pl done
#pragma unroll
        for (int c = 0; c < 2; c++)
            *(s8v*)&El[erow[c] * 72 + ecol] = ereg[c];
        if (tau0 + 64 <= t0) {
#pragma unroll
            for (int c = 0; c < 2; c++)
                ereg[c] = *(const s8v*)(ebase + (size_t)(tau0 + 64 + erow[c]) * 256 + ecol);
        }
        __syncthreads();                       // El ready
        f4v p[4];
#pragma unroll
        for (int fi = 0; fi < 4; fi++) p[fi] = z;
#pragma unroll
        for (int kc = 0; kc < 2; kc++)
#pragma unroll
            for (int fi = 0; fi < 4; fi++) {
                s8v eb = *(s8v*)&El[(fi * 16 + l16) * 72 + kc * 32 + q * 8];
                p[fi] = mfma16(ua[kc], eb, p[fi]);
            }
#pragma unroll
        for (int fi = 0; fi < 4; fi++)
#pragma unroll
            for (int r = 0; r < 4; r++) {
                int tl = w * 16 + q * 4 + r, cl = fi * 16 + l16;
                Pl[tl * 72 + cl] = ((tau0 + cl) <= (t0 + tl)) ? f2b(p[fi][r]) : f2b(0.f);
            }
        __syncthreads();                       // Pl ready
        s8v pb[2][4];
#pragma unroll
        for (int kc = 0; kc < 2; kc++)
#pragma unroll
            for (int tf = 0; tf < 4; tf++)
                pb[kc][tf] = *(s8v*)&Pl[(tf * 16 + l16) * 72 + kc * 32 + q * 8];
#pragma unroll
        for (int zc = 0; zc < 4; zc++)
#pragma unroll
            for (int kc = 0; kc < 2; kc++)
#pragma unroll
                for (int tf = 0; tf < 4; tf++)
                    oacc[zc][tf] = mfma16(vt[zc][kc], pb[kc][tf], oacc[zc][tf]);
    }
    // epilogue: per zc, transpose via LDS and store
    const int trow = tid >> 2, vseg = (tid & 3) * 16;
    for (int zc = 0; zc < 4; zc++) {
        __syncthreads();
#pragma unroll
        for (int tf = 0; tf < 4; tf++)
#pragma unroll
            for (int r = 0; r < 4; r++)
                Ot[(w * 16 + q * 4 + r) * 65 + tf * 16 + l16] = oacc[zc][tf][r];
        __syncthreads();
        bf16 tmp[16];
#pragma unroll
        for (int i = 0; i < 16; i++) tmp[i] = f2b(Ot[(vseg + i) * 65 + trow]);
        size_t o = (size_t)(b * Tn + t0 + trow) * VDn + h * HVn + zc * 64 + vseg;
        *(s8v*)&OV[o] = *(s8v*)&tmp[0];
        *(s8v*)&OV[o + 8] = *(s8v*)&tmp[8];
    }
}

// ---------------------------------------------------------------------------
// Per-(b,t,h) RMS norm over hv=256, * gnorm_w * silu(g). IN-PLACE on OV.
// ---------------------------------------------------------------------------
__global__ __launch_bounds__(256) void norm_gate_kernel(
    bf16* __restrict__ OV, const bf16* __restrict__ G,
    const bf16* __restrict__ gn)
{
    int gid = blockIdx.x;            // B*T*H = 32768
    int h = gid & 3;
    int t = (gid >> 2) & 2047;
    int b = gid >> 13;
    int v = threadIdx.x;
    size_t idx = (size_t)(b * Tn + t) * VDn + h * HVn + v;
    float val = b2f(OV[idx]);
    float ss = val * val;
#pragma unroll
    for (int off = 32; off > 0; off >>= 1) ss += __shfl_down(ss, off, 64);
    __shared__ float red[4];
    int lane = threadIdx.x & 63, wid = threadIdx.x >> 6;
    if (lane == 0) red[wid] = ss;
    __syncthreads();
    float tot = red[0] + red[1] + red[2] + red[3];
    float rs = rsqrtf(tot * (1.0f / 256.0f) + 1e-5f);
    float g = b2f(G[idx]);
    float sg = g / (1.f + expf(-g));
    OV[idx] = f2b(val * rs * b2f(gn[v]) * sg);
}

// ---------------------------------------------------------------------------
extern "C" void kernel_launch(void* const* d_in, const int* in_sizes, int n_in,
                              void* d_out, int out_size, void* d_ws, size_t ws_size,
                              hipStream_t stream)
{
    constexpr size_t MB = 1u << 20;
    char* w = (char*)d_ws;
    bf16* Xb   = (bf16*)(w + 0);               // [0,16)
    bf16* WoT  = (bf16*)(w + 16 * MB);         // [16,18)
    bf16* gnwb = (bf16*)(w + 18 * MB);
    bf16* qwb  = (bf16*)(w + 18 * MB + 4096);
    bf16* kwb  = (bf16*)(w + 18 * MB + 8192);
    bf16* vwb  = (bf16*)(w + 18 * MB + 16384);
    bf16* WqT  = (bf16*)(w + 19 * MB);         // [19,20)
    bf16* WkT  = (bf16*)(w + 20 * MB);         // [20,21)
    bf16* WvT  = (bf16*)(w + 21 * MB);         // [21,23)
    bf16* WsT  = (bf16*)(w + 23 * MB);         // [23,23.5)
    bf16* WgT  = (bf16*)(w + 24 * MB);         // [24,26)
    bf16* preB = (bf16*)(w + 26 * MB);         // [26,42) pre-activations
    bf16* Ebuf = (bf16*)(w + 26 * MB);         // [26,30) after convs
    bf16* ETb  = (bf16*)(w + 30 * MB);         // [30,34)
    float* Cbuf = (float*)(w + 34 * MB);       // [34,42)
    bf16* ghat = (bf16*)(w + 26 * MB);         // [26,42) after attn2
    bf16* Qb   = (bf16*)(w + 42 * MB);         // [42,50)
    bf16* Kb   = (bf16*)(w + 50 * MB);         // [50,58)
    bf16* OVb  = (bf16*)(w + 42 * MB);         // [42,58) after attn1
    bf16* Ubuf = (bf16*)(w + 58 * MB);         // [58,62)
    int*  flagp = (int*)(w + 62 * MB);
    bf16* VT   = (bf16*)d_out;                 // V^T staged in d_out

    dim3 blk(256);
    probe_dtype_kernel<<<1, blk, 0, stream>>>(d_in[0], flagp);
    convert_kernel<<<8192, blk, 0, stream>>>(d_in[0], Xb, flagp, BT * Dn);
    convert_t_kernel<<<dim3(KDn / 64, Dn / 64), blk, 0, stream>>>(d_in[1], WqT, flagp, Dn, KDn);
    convert_t_kernel<<<dim3(KDn / 64, Dn / 64), blk, 0, stream>>>(d_in[2], WkT, flagp, Dn, KDn);
    convert_t_kernel<<<dim3(VDn / 64, Dn / 64), blk, 0, stream>>>(d_in[3], WvT, flagp, Dn, VDn);
    convert_t_kernel<<<dim3(256 / 64, Dn / 64), blk, 0, stream>>>(d_in[4], WsT, flagp, Dn, 256);
    convert_t_kernel<<<dim3(VDn / 64, Dn / 64), blk, 0, stream>>>(d_in[5], WgT, flagp, Dn, VDn);
    convert_t_kernel<<<dim3(Dn / 64, VDn / 64), blk, 0, stream>>>(d_in[6], WoT, flagp, VDn, Dn);
    convert_kernel<<<2, blk, 0, stream>>>(d_in[7], qwb, flagp, KDn * 4);
    convert_kernel<<<2, blk, 0, stream>>>(d_in[8], kwb, flagp, KDn * 4);
    convert_kernel<<<4, blk, 0, stream>>>(d_in[9], vwb, flagp, VDn * 4);
    convert_kernel<<<1, blk, 0, stream>>>(d_in[10], gnwb, flagp, HVn);
    // q path
    gemm_mfma<0><<<dim3(4, 64), blk, 0, stream>>>(Xb, WqT, preB, nullptr, flagp, BT, KDn, Dn);
    conv_qk_rope_kernel<<<8192, blk, 0, stream>>>(preB, qwb, Qb);
    // k path
    gemm_mfma<0><<<dim3(4, 64), blk, 0, stream>>>(Xb, WkT, preB, nullptr, flagp, BT, KDn, Dn);
    conv_qk_rope_kernel<<<8192, blk, 0, stream>>>(preB, kwb, Kb);
    // v path -> VT in d_out
    gemm_mfma<0><<<dim3(8, 64), blk, 0, stream>>>(Xb, WvT, preB, nullptr, flagp, BT, VDn, Dn);
    conv_v_t_kernel<<<dim3(16, 32, 4), blk, 0, stream>>>(preB, vwb, VT);
    // slot gates: E (and ET) = exp(clip(X@Ws)); C = cumsum(ET)
    gemm_mfma<2><<<dim3(2, 64), blk, 0, stream>>>(Xb, WsT, Ebuf, ETb, flagp, BT, 256, Dn);
    cumsum_kernel<<<256, blk, 0, stream>>>(ETb, Cbuf);
    // attention-form passes (grid.x = bh for XCD/L2 locality, y reversed)
    attn1_mfma<<<dim3(16, 32), blk, 0, stream>>>(Qb, Kb, ETb, Cbuf, Ubuf);
    attn2_mfma<<<dim3(16, 32), blk, 0, stream>>>(Ubuf, Ebuf, VT, OVb);
    // gate projection + norm
    gemm_mfma<0><<<dim3(8, 64), blk, 0, stream>>>(Xb, WgT, ghat, nullptr, flagp, BT, VDn, Dn);
    norm_gate_kernel<<<32768, blk, 0, stream>>>(OVb, ghat, gnwb);
    // output projection
    gemm_mfma<3><<<dim3(8, 64), blk, 0, stream>>>(OVb, WoT, d_out, nullptr, flagp, BT, Dn, VDn);
}

// Round 6
// 462.984 us; speedup vs baseline: 10.8958x; 1.0746x over previous
//
#include <hip/hip_runtime.h>
#include <hip/hip_bf16.h>
#include <math.h>

typedef __hip_bfloat16 bf16;
typedef short s8v __attribute__((ext_vector_type(8)));
typedef short s4v __attribute__((ext_vector_type(4)));
typedef float f4v __attribute__((ext_vector_type(4)));

__device__ __forceinline__ float b2f(bf16 x) { return __bfloat162float(x); }
__device__ __forceinline__ bf16 f2b(float x) { return __float2bfloat16(x); }
__device__ __forceinline__ f4v mfma16(s8v a, s8v b, f4v c) {
    return __builtin_amdgcn_mfma_f32_16x16x32_bf16(a, b, c, 0, 0, 0);
}
// async global->LDS, 16B per lane, LDS dst = wave-uniform base + lane*16
__device__ __forceinline__ void async16(const bf16* g, bf16* l) {
    __builtin_amdgcn_global_load_lds(
        (const __attribute__((address_space(1))) void*)g,
        (__attribute__((address_space(3))) void*)l, 16, 0, 0);
}

// Problem constants
constexpr int Bn = 4, Tn = 2048, Dn = 1024, KDn = 512, VDn = 1024;
constexpr int Hn = 4, Mn = 64, HKn = 128, HVn = 256;
constexpr int BT = Bn * Tn; // 8192

// ---------------------------------------------------------------------------
// Dtype probe (fp32 vs bf16 inputs).
// ---------------------------------------------------------------------------
__global__ __launch_bounds__(256) void probe_dtype_kernel(
    const void* __restrict__ x, int* __restrict__ flag)
{
    const bf16* xb = (const bf16*)x;
    float mx = 0.f;
    for (int i = threadIdx.x; i < 4096; i += 256) {
        float v = fabsf(b2f(xb[i]));
        if (isnan(v)) v = 1e30f;
        mx = fmaxf(mx, v);
    }
    __shared__ float red[256];
    red[threadIdx.x] = mx;
    __syncthreads();
    for (int s = 128; s > 0; s >>= 1) {
        if (threadIdx.x < s) red[threadIdx.x] = fmaxf(red[threadIdx.x], red[threadIdx.x + s]);
        __syncthreads();
    }
    if (threadIdx.x == 0) flag[0] = (red[0] > 1e6f) ? 1 : 0;
}

__global__ __launch_bounds__(256) void convert_kernel(
    const void* __restrict__ src, bf16* __restrict__ dst,
    const int* __restrict__ flag, int n)
{
    int is32 = flag[0];
    int i0 = (blockIdx.x * 256 + threadIdx.x) * 4;
#pragma unroll
    for (int j = 0; j < 4; j++) {
        int i = i0 + j;
        if (i < n)
            dst[i] = is32 ? f2b(((const float*)src)[i]) : ((const bf16*)src)[i];
    }
}

// All small 1-D weights in one block: qw(2048) kw(2048) vw(4096) gnw(256)
__global__ __launch_bounds__(256) void convert_small_kernel(
    const void* __restrict__ q, const void* __restrict__ k,
    const void* __restrict__ v, const void* __restrict__ g,
    bf16* __restrict__ qd, bf16* __restrict__ kd,
    bf16* __restrict__ vd, bf16* __restrict__ gd,
    const int* __restrict__ flag)
{
    int is32 = flag[0];
    for (int i = threadIdx.x; i < 8448; i += 256) {
        const void* s; bf16* d; int l;
        if (i < 2048)      { s = q; d = qd; l = i; }
        else if (i < 4096) { s = k; d = kd; l = i - 2048; }
        else if (i < 8192) { s = v; d = vd; l = i - 4096; }
        else               { s = g; d = gd; l = i - 8192; }
        d[l] = is32 ? f2b(((const float*)s)[l]) : ((const bf16*)s)[l];
    }
}

// All six weight transposes in one launch. W[K][N] -> WT[N][K] bf16.
__global__ __launch_bounds__(256) void convert_t6_kernel(
    const void* s0, const void* s1, const void* s2, const void* s3,
    const void* s4, const void* s5,
    bf16* d0, bf16* d1, bf16* d2, bf16* d3, bf16* d4, bf16* d5,
    const int* __restrict__ flag)
{
    __shared__ bf16 tile[64 * 72];
    int is32 = flag[0];
    int nb = blockIdx.x;
    const void* src; bf16* dst; int K, N, loc;
    if (nb < 128)       { src = s0; dst = d0; K = 1024; N = 512;  loc = nb; }
    else if (nb < 256)  { src = s1; dst = d1; K = 1024; N = 512;  loc = nb - 128; }
    else if (nb < 512)  { src = s2; dst = d2; K = 1024; N = 1024; loc = nb - 256; }
    else if (nb < 576)  { src = s3; dst = d3; K = 1024; N = 256;  loc = nb - 512; }
    else if (nb < 832)  { src = s4; dst = d4; K = 1024; N = 1024; loc = nb - 576; }
    else                { src = s5; dst = d5; K = 1024; N = 1024; loc = nb - 832; }
    int nt = N >> 6;
    int n0 = (loc % nt) * 64, k0 = (loc / nt) * 64;
    int tid = threadIdx.x;
    int r = tid >> 2, seg = (tid & 3) * 16;
#pragma unroll
    for (int i = 0; i < 16; i++) {
        size_t gi = (size_t)(k0 + r) * N + n0 + seg + i;
        float v = is32 ? ((const float*)src)[gi] : b2f(((const bf16*)src)[gi]);
        tile[r * 72 + seg + i] = f2b(v);
    }
    __syncthreads();
    bf16 tmp[16];
#pragma unroll
    for (int i = 0; i < 16; i++) tmp[i] = tile[(seg + i) * 72 + r];
    size_t o = (size_t)(n0 + r) * K + k0 + seg;
    *(s8v*)&dst[o] = *(s8v*)&tmp[0];
    *(s8v*)&dst[o + 8] = *(s8v*)&tmp[8];
}

// ---------------------------------------------------------------------------
// MFMA GEMM w/ global_load_lds (m97 recipe): C[M,N] = A[M,K] * BT[N,K]^T.
// 128x128 tile, BK=64, unpadded lane-ordered LDS tiles.
// EP: 0 bf16; 2 exp-clip dual-store (E + ET); 3 dynamic fp32/bf16.
// ---------------------------------------------------------------------------
template <int EP>
__global__ __launch_bounds__(256) void gemm_mfma(
    const bf16* __restrict__ A, const bf16* __restrict__ BT,
    void* __restrict__ Cout, bf16* __restrict__ Cout2,
    const int* __restrict__ flag, int M, int N, int K)
{
    __shared__ bf16 Xs[128 * 64];
    __shared__ bf16 Ws2[128 * 64];
    const int tid = threadIdx.x;
    const int w = tid >> 6, lane = tid & 63;
    const int l16 = lane & 15, q = lane >> 4;
    const int wr = w >> 1, wc = w & 1;
    const int m0 = blockIdx.y * 128, n0 = blockIdx.x * 128;
    int dyn = 0;
    if (EP == 3) dyn = flag[0];

    // staging: per call one wave moves 8 rows x 64 cols (lane -> row lane/8, col (lane&7)*8)
    const int srow = w * 32 + (lane >> 3);
    const int scol = (lane & 7) * 8;
    const bf16* ga = A + (size_t)(m0 + srow) * K + scol;
    const bf16* gb = BT + (size_t)(n0 + srow) * K + scol;

    f4v acc[4][4];
    f4v z = {0.f, 0.f, 0.f, 0.f};
#pragma unroll
    for (int i = 0; i < 4; i++)
#pragma unroll
        for (int j = 0; j < 4; j++) acc[i][j] = z;

    for (int k0 = 0; k0 < K; k0 += 64) {
#pragma unroll
        for (int c = 0; c < 4; c++) {
            async16(ga + (size_t)(c * 8) * K + k0, &Xs[(w * 32 + c * 8) * 64]);
            async16(gb + (size_t)(c * 8) * K + k0, &Ws2[(w * 32 + c * 8) * 64]);
        }
        __syncthreads();   // drains vmcnt: tiles resident
#pragma unroll
        for (int kq = 0; kq < 2; kq++) {
            s8v a[4], b[4];
#pragma unroll
            for (int mi = 0; mi < 4; mi++)
                a[mi] = *(s8v*)&Xs[(wr * 64 + mi * 16 + l16) * 64 + kq * 32 + q * 8];
#pragma unroll
            for (int ni = 0; ni < 4; ni++)
                b[ni] = *(s8v*)&Ws2[(wc * 64 + ni * 16 + l16) * 64 + kq * 32 + q * 8];
#pragma unroll
            for (int mi = 0; mi < 4; mi++)
#pragma unroll
                for (int ni = 0; ni < 4; ni++)
                    acc[mi][ni] = mfma16(a[mi], b[ni], acc[mi][ni]);
        }
        __syncthreads();   // readers done before next DMA overwrites
    }
#pragma unroll
    for (int mi = 0; mi < 4; mi++)
#pragma unroll
        for (int ni = 0; ni < 4; ni++)
#pragma unroll
            for (int r = 0; r < 4; r++) {
                int row = m0 + wr * 64 + mi * 16 + q * 4 + r;
                int col = n0 + wc * 64 + ni * 16 + l16;
                size_t idx = (size_t)row * N + col;
                float v = acc[mi][ni][r];
                if (EP == 2) {
                    float cl = fminf(32.f, fmaxf(-32.f, v));
                    bf16 e = f2b(expf(cl));
                    ((bf16*)Cout)[idx] = e;
                    int b_ = row >> 11, t_ = row & 2047;
                    int h_ = col >> 6, m_ = col & 63;
                    Cout2[((size_t)((b_ * 4 + h_) * 64 + m_)) * 2048 + t_] = e;
                } else if (EP == 3) {
                    if (dyn) ((float*)Cout)[idx] = v;
                    else ((bf16*)Cout)[idx] = f2b(v);
                } else {
                    ((bf16*)Cout)[idx] = f2b(v);
                }
            }
}

// ---------------------------------------------------------------------------
// Depthwise causal conv (KS=4) + SiLU + RoPE for q/k. pre has row stride 1024
// (merged q|k GEMM output), coff selects q (0) or k (512) columns.
// ---------------------------------------------------------------------------
__global__ __launch_bounds__(256) void conv_qk_rope_kernel(
    const bf16* __restrict__ pre, const bf16* __restrict__ w,
    bf16* __restrict__ out, int coff)
{
    int gid = blockIdx.x * 256 + threadIdx.x;  // B*T*H*64
    int d = gid & 63;
    int h = (gid >> 6) & 3;
    int t = (gid >> 8) & 2047;
    int b = gid >> 19;
    int clo = h * HKn + d, chi = clo + 64;
    float ylo = 0.f, yhi = 0.f;
#pragma unroll
    for (int j = 0; j < 4; j++) {
        int tt = t - 3 + j;
        if (tt >= 0) {
            size_t rb = (size_t)(b * Tn + tt) * 1024 + coff;
            ylo += b2f(pre[rb + clo]) * b2f(w[clo * 4 + j]);
            yhi += b2f(pre[rb + chi]) * b2f(w[chi * 4 + j]);
        }
    }
    ylo = ylo / (1.f + expf(-ylo));
    yhi = yhi / (1.f + expf(-yhi));
    float invf = powf(10000.f, -(float)d * (1.f / 64.f));
    float th = (float)t * invf;
    float c = cosf(th), s = sinf(th);
    size_t rowbase = (size_t)(b * Tn + t) * KDn;
    out[rowbase + clo] = f2b(ylo * c - yhi * s);
    out[rowbase + chi] = f2b(yhi * c + ylo * s);
}

// ---------------------------------------------------------------------------
// conv + silu for v, writing V TRANSPOSED: VT[b*1024 + c][t]. 64x64 tiles.
// ---------------------------------------------------------------------------
__global__ __launch_bounds__(256) void conv_v_t_kernel(
    const bf16* __restrict__ pre, const bf16* __restrict__ w,
    bf16* __restrict__ VT)
{
    __shared__ bf16 tile[64 * 72];
    int c0 = blockIdx.x * 64, t0 = blockIdx.y * 64, b = blockIdx.z;
    int tid = threadIdx.x;
    int row = tid >> 2, seg = (tid & 3) * 16;
    float y[16];
#pragma unroll
    for (int i = 0; i < 16; i++) y[i] = 0.f;
#pragma unroll
    for (int j = 0; j < 4; j++) {
        int tt = t0 + row - 3 + j;
        if (tt >= 0) {
            const bf16* p = &pre[(size_t)(b * Tn + tt) * VDn + c0 + seg];
#pragma unroll
            for (int i = 0; i < 16; i++)
                y[i] += b2f(p[i]) * b2f(w[(c0 + seg + i) * 4 + j]);
        }
    }
#pragma unroll
    for (int i = 0; i < 16; i++) {
        float v = y[i] / (1.f + expf(-y[i]));
        tile[row * 72 + seg + i] = f2b(v);
    }
    __syncthreads();
    bf16 tmp[16];
#pragma unroll
    for (int i = 0; i < 16; i++) tmp[i] = tile[(seg + i) * 72 + row];
    size_t o = (size_t)(b * 1024 + c0 + row) * 2048 + t0 + seg;
    *(s8v*)&VT[o] = *(s8v*)&tmp[0];
    *(s8v*)&VT[o + 8] = *(s8v*)&tmp[8];
}

// ---------------------------------------------------------------------------
// cumsum over tau per (b,h,m) row of ET; wave-parallel scan. C fp32 [b][t][hm].
// ---------------------------------------------------------------------------
__global__ __launch_bounds__(256) void cumsum_kernel(
    const bf16* __restrict__ ET, float* __restrict__ C)
{
    int row = blockIdx.x * 4 + (threadIdx.x >> 6);   // 1024 rows
    int lane = threadIdx.x & 63;
    int b = row >> 8, hm = row & 255;
    const bf16* src = ET + (size_t)row * 2048;
    float run = 0.f;
    for (int ch = 0; ch < 32; ch++) {
        float v = b2f(src[ch * 64 + lane]);
#pragma unroll
        for (int off = 1; off < 64; off <<= 1) {
            float o = __shfl_up(v, off, 64);
            if (lane >= off) v += o;
        }
        C[(size_t)(b * 2048 + ch * 64 + lane) * 256 + hm] = run + v;
        run += __shfl(v, 63, 64);
    }
}

// ---------------------------------------------------------------------------
// attn1 (MFMA): S^T = K Q^T (swapped operands -> packed b64 LDS stores),
// okT += ET * S^T, softmax -> U.  grid (bh=16, ttile=32 reversed).
// ---------------------------------------------------------------------------
__global__ __launch_bounds__(256) void attn1_mfma(
    const bf16* __restrict__ Q, const bf16* __restrict__ K,
    const bf16* __restrict__ ET, const float* __restrict__ C,
    bf16* __restrict__ U)
{
    __shared__ bf16 Kl[64 * 136];
    __shared__ bf16 Sl[64 * 72];
    __shared__ float okT[64 * 65];
    const int tid = threadIdx.x;
    const int w = tid >> 6, lane = tid & 63;
    const int l16 = lane & 15, q = lane >> 4;
    const int b = blockIdx.x >> 2, h = blockIdx.x & 3;
    const int t0 = (int)(gridDim.y - 1 - blockIdx.y) * 64;
    f4v z = {0.f, 0.f, 0.f, 0.f};

    const bf16* qrow = Q + (size_t)(b * Tn + t0 + w * 16 + l16) * KDn + h * HKn;
    s8v qa[4];
#pragma unroll
    for (int kc = 0; kc < 4; kc++) qa[kc] = *(const s8v*)(qrow + kc * 32 + q * 8);
    const bf16* etrow = ET + (size_t)((b * 4 + h) * 64 + w * 16 + l16) * 2048;
    const int krow[4] = {(0 * 256 + tid) >> 4, (1 * 256 + tid) >> 4,
                         (2 * 256 + tid) >> 4, (3 * 256 + tid) >> 4};
    const int kcol = (tid & 15) * 8;
    const bf16* kbase = K + (size_t)b * Tn * KDn + h * HKn;

    f4v ok[4];
#pragma unroll
    for (int i = 0; i < 4; i++) ok[i] = z;

    s8v kreg[4];
#pragma unroll
    for (int c = 0; c < 4; c++)
        kreg[c] = *(const s8v*)(kbase + (size_t)(0 + krow[c]) * KDn + kcol);

    for (int tau0 = 0; tau0 <= t0; tau0 += 64) {
        s8v ea[2];
#pragma unroll
        for (int kc = 0; kc < 2; kc++) ea[kc] = *(const s8v*)(etrow + tau0 + kc * 32 + q * 8);
        __syncthreads();
#pragma unroll
        for (int c = 0; c < 4; c++)
            *(s8v*)&Kl[krow[c] * 136 + kcol] = kreg[c];
        if (tau0 + 64 <= t0) {
#pragma unroll
            for (int c = 0; c < 4; c++)
                kreg[c] = *(const s8v*)(kbase + (size_t)(tau0 + 64 + krow[c]) * KDn + kcol);
        }
        __syncthreads();
        // S^T: rows = tau (fi group), cols = t (this wave's 16 t's)
        f4v sT[4];
#pragma unroll
        for (int fi = 0; fi < 4; fi++) sT[fi] = z;
#pragma unroll
        for (int kc = 0; kc < 4; kc++)
#pragma unroll
            for (int fi = 0; fi < 4; fi++) {
                s8v kb = *(s8v*)&Kl[(fi * 16 + l16) * 136 + kc * 32 + q * 8];
                sT[fi] = mfma16(kb, qa[kc], sT[fi]);
            }
        const int tl = w * 16 + l16;
#pragma unroll
        for (int fi = 0; fi < 4; fi++) {
            alignas(8) bf16 pk[4];
#pragma unroll
            for (int r = 0; r < 4; r++) {
                int taul = fi * 16 + q * 4 + r;
                float v = sT[fi][r] * 0.08838834764831845f;
                pk[r] = ((tau0 + taul) <= (t0 + tl)) ? f2b(v) : f2b(0.f);
            }
            *(s4v*)&Sl[tl * 72 + fi * 16 + q * 4] = *(s4v*)pk;
        }
        __syncthreads();
#pragma unroll
        for (int kc = 0; kc < 2; kc++)
#pragma unroll
            for (int tf = 0; tf < 4; tf++) {
                s8v sb = *(s8v*)&Sl[(tf * 16 + l16) * 72 + kc * 32 + q * 8];
                ok[tf] = mfma16(ea[kc], sb, ok[tf]);
            }
    }
    __syncthreads();
#pragma unroll
    for (int tf = 0; tf < 4; tf++)
#pragma unroll
        for (int r = 0; r < 4; r++)
            okT[(w * 16 + q * 4 + r) * 65 + tf * 16 + l16] = ok[tf][r];
    __syncthreads();
    if (tid < 64) {
        int t = tid;
        size_t base = (size_t)(b * Tn + t0 + t) * 256 + h * 64;
        float mx = -1e30f;
        for (int m = 0; m < 64; m++) {
            float v = okT[m * 65 + t] / C[base + m];
            okT[m * 65 + t] = v;
            mx = fmaxf(mx, v);
        }
        float sum = 0.f;
        for (int m = 0; m < 64; m++) {
            float e = expf(okT[m * 65 + t] - mx);
            okT[m * 65 + t] = e;
            sum += e;
        }
        float inv = 1.f / sum;
        for (int m = 0; m < 64; m++)
            U[base + m] = f2b(okT[m * 65 + t] * inv / C[base + m]);
    }
}

// ---------------------------------------------------------------------------
// attn2 (MFMA): P^T = E U^T (packed b64 stores), O^T += VT * P^T, then FUSED
// RMSNorm * gnorm * silu(ghat) epilogue. grid (bh=16, ttile=32 reversed).
// ---------------------------------------------------------------------------
__global__ __launch_bounds__(256) void attn2_mfma(
    const bf16* __restrict__ U, const bf16* __restrict__ E,
    const bf16* __restrict__ VT, const bf16* __restrict__ G,
    const bf16* __restrict__ gn, bf16* __restrict__ OV)
{
    __shared__ bf16 El[64 * 72];
    __shared__ bf16 Pl[64 * 72];
    __shared__ float Ot[64 * 65];
    __shared__ float ssum[64];
    const int tid = threadIdx.x;
    const int w = tid >> 6, lane = tid & 63;
    const int l16 = lane & 15, q = lane >> 4;
    const int b = blockIdx.x >> 2, h = blockIdx.x & 3;
    const int t0 = (int)(gridDim.y - 1 - blockIdx.y) * 64;
    f4v z = {0.f, 0.f, 0.f, 0.f};

    const bf16* urow = U + (size_t)(b * Tn + t0 + w * 16 + l16) * 256 + h * 64;
    s8v ua[2];
#pragma unroll
    for (int kc = 0; kc < 2; kc++) ua[kc] = *(const s8v*)(urow + kc * 32 + q * 8);
    const bf16* ebase = E + (size_t)b * Tn * 256 + h * 64;
    const int erow[2] = {(0 * 256 + tid) >> 3, (1 * 256 + tid) >> 3};
    const int ecol = (tid & 7) * 8;
    const bf16* vtbase = VT + (size_t)(b * 1024 + h * 256 + w * 16 + l16) * 2048;

    f4v oacc[4][4];
#pragma unroll
    for (int zc = 0; zc < 4; zc++)
#pragma unroll
        for (int i = 0; i < 4; i++) oacc[zc][i] = z;
    if (tid < 64) ssum[tid] = 0.f;

    s8v ereg[2];
#pragma unroll
    for (int c = 0; c < 2; c++)
        ereg[c] = *(const s8v*)(ebase + (size_t)(0 + erow[c]) * 256 + ecol);

    for (int tau0 = 0; tau0 <= t0; tau0 += 64) {
        s8v vt[4][2];
#pragma unroll
        for (int zc = 0; zc < 4; zc++)
#pragma unroll
            for (int kc = 0; kc < 2; kc++)
                vt[zc][kc] = *(const s8v*)(vtbase + (size_t)(zc * 64) * 2048
                                           + tau0 + kc * 32 + q * 8);
        __syncthreads();
#pragma unroll
        for (int c = 0; c < 2; c++)
            *(s8v*)&El[erow[c] * 72 + ecol] = ereg[c];
        if (tau0 + 64 <= t0) {
#pragma unroll
            for (int c = 0; c < 2; c++)
                ereg[c] = *(const s8v*)(ebase + (size_t)(tau0 + 64 + erow[c]) * 256 + ecol);
        }
        __syncthreads();
        // P^T: rows = tau (fi group), cols = t (wave's 16 t's)
        f4v pT[4];
#pragma unroll
        for (int fi = 0; fi < 4; fi++) pT[fi] = z;
#pragma unroll
        for (int kc = 0; kc < 2; kc++)
#pragma unroll
            for (int fi = 0; fi < 4; fi++) {
                s8v eb = *(s8v*)&El[(fi * 16 + l16) * 72 + kc * 32 + q * 8];
                pT[fi] = mfma16(eb, ua[kc], pT[fi]);
            }
        const int tl = w * 16 + l16;
#pragma unroll
        for (int fi = 0; fi < 4; fi++) {
            alignas(8) bf16 pk[4];
#pragma unroll
            for (int r = 0; r < 4; r++) {
                int taul = fi * 16 + q * 4 + r;
                pk[r] = ((tau0 + taul) <= (t0 + tl)) ? f2b(pT[fi][r]) : f2b(0.f);
            }
            *(s4v*)&Pl[tl * 72 + fi * 16 + q * 4] = *(s4v*)pk;
        }
        __syncthreads();
        s8v pb[2][4];
#pragma unroll
        for (int kc = 0; kc < 2; kc++)
#pragma unroll
            for (int tf = 0; tf < 4; tf++)
                pb[kc][tf] = *(s8v*)&Pl[(tf * 16 + l16) * 72 + kc * 32 + q * 8];
#pragma unroll
        for (int zc = 0; zc < 4; zc++)
#pragma unroll
            for (int kc = 0; kc < 2; kc++)
#pragma unroll
                for (int tf = 0; tf < 4; tf++)
                    oacc[zc][tf] = mfma16(vt[zc][kc], pb[kc][tf], oacc[zc][tf]);
    }
    // fused RMSNorm: sum of squares over all 256 v per t
    __syncthreads();
    float part[4] = {0.f, 0.f, 0.f, 0.f};
#pragma unroll
    for (int zc = 0; zc < 4; zc++)
#pragma unroll
        for (int tf = 0; tf < 4; tf++)
#pragma unroll
            for (int r = 0; r < 4; r++)
                part[tf] += oacc[zc][tf][r] * oacc[zc][tf][r];
#pragma unroll
    for (int tf = 0; tf < 4; tf++)
        atomicAdd(&ssum[tf * 16 + l16], part[tf]);
    __syncthreads();
    if (tid < 64) ssum[tid] = rsqrtf(ssum[tid] * (1.0f / 256.0f) + 1e-5f);
    __syncthreads();
    // epilogue: per zc, transpose via LDS, apply norm * gn * silu(g), store
    const int trow = tid >> 2, vseg = (tid & 3) * 16;
    for (int zc = 0; zc < 4; zc++) {
#pragma unroll
        for (int tf = 0; tf < 4; tf++)
#pragma unroll
            for (int r = 0; r < 4; r++)
                Ot[(w * 16 + q * 4 + r) * 65 + tf * 16 + l16] = oacc[zc][tf][r];
        __syncthreads();
        float rs = ssum[trow];
        size_t grow = (size_t)(b * Tn + t0 + trow) * VDn + h * HVn + zc * 64 + vseg;
        alignas(16) bf16 gh[16];
        *(s8v*)&gh[0] = *(const s8v*)&G[grow];
        *(s8v*)&gh[8] = *(const s8v*)&G[grow + 8];
        alignas(16) bf16 tmp[16];
#pragma unroll
        for (int i = 0; i < 16; i++) {
            float g = b2f(gh[i]);
            float sg = g / (1.f + expf(-g));
            float val = Ot[(vseg + i) * 65 + trow] * rs * b2f(gn[zc * 64 + vseg + i]) * sg;
            tmp[i] = f2b(val);
        }
        *(s8v*)&OV[grow] = *(s8v*)&tmp[0];
        *(s8v*)&OV[grow + 8] = *(s8v*)&tmp[8];
        __syncthreads();
    }
}

// ---------------------------------------------------------------------------
extern "C" void kernel_launch(void* const* d_in, const int* in_sizes, int n_in,
                              void* d_out, int out_size, void* d_ws, size_t ws_size,
                              hipStream_t stream)
{
    constexpr size_t MB = 1u << 20;
    char* w = (char*)d_ws;
    bf16* Xb   = (bf16*)(w + 0);                 // [0,16)  ; later OV
    bf16* OVb  = (bf16*)(w + 0);
    bf16* WoT  = (bf16*)(w + 16 * MB);           // [16,18)
    bf16* WgT  = (bf16*)(w + 18 * MB);           // [18,20)
    bf16* WqT  = (bf16*)(w + 20 * MB);           // [20,21)  (WkT contiguous after)
    bf16* WkT  = (bf16*)(w + 21 * MB);           // [21,22)
    bf16* WvT  = (bf16*)(w + 22 * MB);           // [22,24)
    bf16* WsT  = (bf16*)(w + 24 * MB);           // [24,24.5)
    bf16* gnwb = (bf16*)(w + 24 * MB + 524288);  // smalls in [24.5,25)
    bf16* qwb  = (bf16*)(w + 24 * MB + 532480);
    bf16* kwb  = (bf16*)(w + 24 * MB + 540672);
    bf16* vwb  = (bf16*)(w + 24 * MB + 548864);
    int*  flagp= (int*) (w + 24 * MB + 565248);
    bf16* Qb   = (bf16*)(w + 25 * MB);           // [25,33) ; later ghat [25,41)
    bf16* Kb   = (bf16*)(w + 33 * MB);           // [33,41)
    bf16* ghat = (bf16*)(w + 25 * MB);
    bf16* qkpre= (bf16*)(w + 41 * MB);           // [41,57) ; later E/ET/C
    bf16* vpre = (bf16*)(w + 41 * MB);
    bf16* Ebuf = (bf16*)(w + 41 * MB);           // [41,45)
    bf16* ETb  = (bf16*)(w + 45 * MB);           // [45,49)
    float* Cbuf= (float*)(w + 49 * MB);          // [49,57)
    bf16* Ubuf = (bf16*)(w + 57 * MB);           // [57,61)
    bf16* VT   = (bf16*)d_out;                   // V^T staged in d_out

    dim3 blk(256);
    probe_dtype_kernel<<<1, blk, 0, stream>>>(d_in[0], flagp);
    convert_kernel<<<16384, blk, 0, stream>>>(d_in[0], Xb, flagp, BT * Dn);
    convert_small_kernel<<<1, blk, 0, stream>>>(d_in[7], d_in[8], d_in[9], d_in[10],
                                                qwb, kwb, vwb, gnwb, flagp);
    convert_t6_kernel<<<1088, blk, 0, stream>>>(d_in[1], d_in[2], d_in[3], d_in[4],
                                                d_in[5], d_in[6],
                                                WqT, WkT, WvT, WsT, WgT, WoT, flagp);
    // merged q|k projection (N=1024: cols 0..511 q, 512..1023 k)
    gemm_mfma<0><<<dim3(8, 64), blk, 0, stream>>>(Xb, WqT, qkpre, nullptr, flagp, BT, 1024, Dn);
    conv_qk_rope_kernel<<<8192, blk, 0, stream>>>(qkpre, qwb, Qb, 0);
    conv_qk_rope_kernel<<<8192, blk, 0, stream>>>(qkpre, kwb, Kb, 512);
    // v projection + transpose conv (vpre overwrites dead qkpre)
    gemm_mfma<0><<<dim3(8, 64), blk, 0, stream>>>(Xb, WvT, vpre, nullptr, flagp, BT, VDn, Dn);
    conv_v_t_kernel<<<dim3(16, 32, 4), blk, 0, stream>>>(vpre, vwb, VT);
    // slot gates: E (and ET) = exp(clip(X@Ws)); C = cumsum(ET)
    gemm_mfma<2><<<dim3(2, 64), blk, 0, stream>>>(Xb, WsT, Ebuf, ETb, flagp, BT, 256, Dn);
    cumsum_kernel<<<256, blk, 0, stream>>>(ETb, Cbuf);
    // attn1 -> U
    attn1_mfma<<<dim3(16, 32), blk, 0, stream>>>(Qb, Kb, ETb, Cbuf, Ubuf);
    // gate projection into dead Qb/Kb region
    gemm_mfma<0><<<dim3(8, 64), blk, 0, stream>>>(Xb, WgT, ghat, nullptr, flagp, BT, VDn, Dn);
    // attn2 with fused norm/gate -> OV (over dead Xb)
    attn2_mfma<<<dim3(16, 32), blk, 0, stream>>>(Ubuf, Ebuf, VT, ghat, gnwb, OVb);
    // output projection
    gemm_mfma<3><<<dim3(8, 64), blk, 0, stream>>>(OVb, WoT, d_out, nullptr, flagp, BT, Dn, VDn);
}